// Round 4
// baseline (2300.565 us; speedup 1.0000x reference)
//
#include <hip/hip_runtime.h>

typedef unsigned short u16;
typedef unsigned int u32;
typedef unsigned long long u64;
typedef __bf16 bf16x8 __attribute__((ext_vector_type(8)));
typedef float f32x4 __attribute__((ext_vector_type(4)));
typedef u16 u16x8 __attribute__((ext_vector_type(8)));
typedef u16 u16x4 __attribute__((ext_vector_type(4)));

struct u64pair { u64 a, b; };

#define MFMA16x16(a,b,c) __builtin_amdgcn_mfma_f32_16x16x32_bf16((a),(b),(c),0,0,0)

static __device__ __forceinline__ u16 f2bf(float f){
  u32 u = __builtin_bit_cast(u32, f);
  u += 0x7fffu + ((u >> 16) & 1u);
  return (u16)(u >> 16);
}
static __device__ __forceinline__ float bf2f(u16 h){
  u32 u = ((u32)h) << 16;
  return __builtin_bit_cast(float, u);
}
static __device__ __forceinline__ float fast_sigmoid(float x){
  return 1.f / (1.f + __expf(-x));
}
static __device__ __forceinline__ float fast_tanh(float x){
  float e = __expf(2.f * x);
  return 1.f - 2.f / (e + 1.f);
}
static __device__ __forceinline__ float fast_softplus(float x){
  return (x > 15.f) ? x : __logf(1.f + __expf(x));
}
static __device__ __forceinline__ f32x4 zero4(){
  f32x4 v; v[0]=0.f; v[1]=0.f; v[2]=0.f; v[3]=0.f; return v;
}

// ---------------------------------------------------------------------------
// Weight swizzle into MFMA B-fragment order:
// dst[ks][nt][lane][j] = W[k = ks*32 + (lane>>4)*8 + j][ncol = nt*16 + (lane&15)]
// modes: 0 GRU hidden  2 post(500x500+b)  3 zW  4 heads  5 enc Wih
// ---------------------------------------------------------------------------
static __device__ __forceinline__ void build_one(
    u16* __restrict__ dst, int mode, int NT, int idx,
    const float* __restrict__ W0, const float* __restrict__ b0,
    const float* __restrict__ W1, const float* __restrict__ b1)
{
  int j    = idx & 7;
  int lane = (idx >> 3) & 63;
  int ntks = idx >> 9;
  int nt   = ntks % NT;
  int ks   = ntks / NT;
  int k    = ks * 32 + ((lane >> 4) << 3) + j;
  int ncol = (nt << 4) + (lane & 15);
  float v = 0.f;
  if (mode == 0){                         // GRU hidden: rows 0..499 Whh^T, 511 bhh
    int g = ncol >> 9;
    int jin = ncol & 511;
    if (jin < 500){
      int row = g * 500 + jin;
      if (k < 500) v = W0[row * 500 + k];
      else if (k == 511) v = b0[row];
    }
  } else if (mode == 2){                  // post: W0 [500][500], bias row 511
    if (ncol < 500){
      if (k < 500) v = W0[ncol * 500 + k];
      else if (k == 511) v = b0[ncol];
    }
  } else if (mode == 3){                  // zW: cols 0..2 zm (W0 [3][503]), 3..5 zs
    int c = ncol;
    if (c < 3){
      if (k < 500) v = W0[c * 503 + k];
      else if (k == 511) v = b0[c];
    } else if (c < 6){
      int cc = c - 3;
      if (k < 500) v = W1[cc * 503 + k];
      else if (k == 511) v = b1[cc];
    }
  } else if (mode == 4){                  // heads: cols 0..47 xm (<38), 48..95 xs
    int grp = ncol / 48;
    int cc  = ncol - grp * 48;
    if (grp < 2 && cc < 38){
      const float* W  = grp ? W1 : W0;
      const float* bb = grp ? b1 : b0;
      if (k < 500) v = W[cc * 500 + k];
      else if (k == 511) v = bb[cc];
    }
  } else {                                // mode 5: enc Wih [1500][38]
    int g = ncol >> 9;
    int jin = ncol & 511;
    if (jin < 500 && k < 38) v = W0[(g * 500 + jin) * 38 + k];
  }
  dst[idx] = f2bf(v);
}

// One launch for all weight prep + flow param precompute (was 10 launches).
__global__ void build_all(
    u16* ENCF, u16* DECF, u16* EGIF, u16* PF0, u16* PF1, u16* PF2, u16* PF3,
    u16* ZFR, u16* HFR, float* FPP,
    const float* enc_Whh, const float* enc_bhh, const float* enc_Wih,
    const float* dec_Whh, const float* dec_bhh,
    const float* enc_W1, const float* enc_b1, const float* enc_W2, const float* enc_b2,
    const float* dec_W1, const float* dec_b1, const float* dec_W2, const float* dec_b2,
    const float* zm_W, const float* zm_b, const float* zs_W, const float* zs_b,
    const float* xm_W, const float* xm_b, const float* xs_W, const float* xs_b,
    const float* flow_w, const float* flow_b, const float* flow_u)
{
  const int b = blockIdx.x, tid = threadIdx.x;
  if      (b < 3072)  build_one(ENCF,0,96,(b       )*256+tid, enc_Whh,enc_bhh,0,0);
  else if (b < 6144)  build_one(DECF,0,96,(b- 3072 )*256+tid, dec_Whh,dec_bhh,0,0);
  else if (b < 6528)  build_one(EGIF,5,96,(b- 6144 )*256+tid, enc_Wih,0,0,0);
  else if (b < 7552)  build_one(PF0 ,2,32,(b- 6528 )*256+tid, enc_W1,enc_b1,0,0);
  else if (b < 8576)  build_one(PF1 ,2,32,(b- 7552 )*256+tid, enc_W2,enc_b2,0,0);
  else if (b < 9600)  build_one(PF2 ,2,32,(b- 8576 )*256+tid, dec_W1,dec_b1,0,0);
  else if (b < 10624) build_one(PF3 ,2,32,(b- 9600 )*256+tid, dec_W2,dec_b2,0,0);
  else if (b < 10656) build_one(ZFR ,3, 1,(b-10624 )*256+tid, zm_W,zm_b,zs_W,zs_b);
  else if (b < 10848) build_one(HFR ,4, 6,(b-10656 )*256+tid, xm_W,xm_b,xs_W,xs_b);
  else if (tid < 20){
    int l = tid;
    float w0 = flow_w[l*3+0], w1 = flow_w[l*3+1], w2 = flow_w[l*3+2];
    float u0 = flow_u[l*3+0], u1 = flow_u[l*3+1], u2 = flow_u[l*3+2];
    float wu = w0*u0 + w1*u1 + w2*u2;
    float m  = -1.f + fast_softplus(wu);
    float ww = w0*w0 + w1*w1 + w2*w2 + 1e-7f;
    float sc = (m - wu) / ww;
    float uh0 = u0 + sc*w0, uh1 = u1 + sc*w1, uh2 = u2 + sc*w2;
    float uw  = uh0*w0 + uh1*w1 + uh2*w2;
    FPP[l*8+0]=w0; FPP[l*8+1]=w1; FPP[l*8+2]=w2; FPP[l*8+3]=flow_b[l];
    FPP[l*8+4]=uh0; FPP[l*8+5]=uh1; FPP[l*8+6]=uh2; FPP[l*8+7]=uw;
  }
}

// ---------------------------------------------------------------------------
// Encoder input-gates precompute: gi[51200][1536] = x[51200][38] @ Wih^T + bih
// ---------------------------------------------------------------------------
__global__ __launch_bounds__(512, 2) void gi_enc_kernel(
    const float* __restrict__ x, const u16* __restrict__ frag2,
    const float* __restrict__ bih, u16* __restrict__ gi)
{
  const int tid = threadIdx.x, lane = tid & 63, v = tid >> 6;
  const int q = lane >> 4, c = lane & 15;
  const size_t rowbase = (size_t)blockIdx.x * 32;
  u16 a[2][2][8];
  #pragma unroll
  for (int tile = 0; tile < 2; ++tile){
    const float* xr = x + (rowbase + tile*16 + c) * 38;
    #pragma unroll
    for (int j = 0; j < 8; ++j){
      int k0 = q*8 + j;
      a[tile][0][j] = f2bf(xr[k0]);
      int k1 = 32 + q*8 + j;
      a[tile][1][j] = (k1 < 38) ? f2bf(xr[k1]) : (u16)0;
    }
  }
  f32x4 acc[2][12];
  #pragma unroll
  for (int tile = 0; tile < 2; ++tile)
    #pragma unroll
    for (int i = 0; i < 12; ++i) acc[tile][i] = zero4();
  #pragma unroll
  for (int i = 0; i < 12; ++i){
    const int nt = v*12 + i;
    bf16x8 b0 = __builtin_bit_cast(bf16x8,
        *(const u16x8*)(frag2 + (((size_t)0*96 + nt)*64 + lane)*8));
    bf16x8 b1 = __builtin_bit_cast(bf16x8,
        *(const u16x8*)(frag2 + (((size_t)1*96 + nt)*64 + lane)*8));
    #pragma unroll
    for (int tile = 0; tile < 2; ++tile){
      bf16x8 a0 = __builtin_bit_cast(bf16x8, *(const u16x8*)a[tile][0]);
      bf16x8 a1 = __builtin_bit_cast(bf16x8, *(const u16x8*)a[tile][1]);
      acc[tile][i] = MFMA16x16(a0, b0, acc[tile][i]);
      acc[tile][i] = MFMA16x16(a1, b1, acc[tile][i]);
    }
  }
  #pragma unroll
  for (int i = 0; i < 12; ++i){
    const int nt = v*12 + i;
    const int ncol = nt*16 + c;
    const int g = ncol >> 9, jin = ncol & 511;
    const float bias = (jin < 500) ? bih[g*500 + jin] : 0.f;
    #pragma unroll
    for (int tile = 0; tile < 2; ++tile)
      #pragma unroll
      for (int r = 0; r < 4; ++r){
        size_t row = rowbase + tile*16 + q*4 + r;
        gi[row*1536 + ncol] = f2bf(acc[tile][i][r] + bias);
      }
  }
}

// ---------------------------------------------------------------------------
// Register-resident cooperative GRU, free-running waves.
// Grid 256 = 32 batch-groups x 8 col-slices; 8 waves = 4 nt x 2 K-halves.
// Sync: per storing wave, sc1 h-stores -> s_waitcnt(0) -> relaxed add (+1);
// readers: ALL waves poll (same-address broadcast load) for 32*(t+1), then go.
// ONE __syncthreads per step (LDS K-half reduction). Correctness: a block's
// adds for step t are ordered after its reduction barrier, hence after all
// its h_t reads -> buffer reuse at t+2 cannot race a straggler.
// enc: gi streamed from gix. dec: gi computed on the fly from z (rank 3).
// 84 KB LDS forces 1 block/CU.
// ---------------------------------------------------------------------------
__global__ __launch_bounds__(512, 2) void gru3_kernel(
    const u16* __restrict__ frag, const u16* __restrict__ gix,
    const u64* __restrict__ zsrc, const float* __restrict__ Wih3,
    const float* __restrict__ bih3,
    u32* __restrict__ hbufbase, u16* __restrict__ hout, u32* __restrict__ cnt_)
{
  __shared__ f32x4 red[5376];               // 86016 B: forces 1 block/CU
  const int tid  = threadIdx.x, lane = tid & 63;
  const int wv   = tid >> 6, igrp = wv & 3, half = wv >> 2;
  const int q    = lane >> 4, c = lane & 15;
  const int gid  = blockIdx.x & 31, s = blockIdx.x >> 5;
  const int b0   = gid * 16;
  const int col  = (s*4 + igrp)*16 + c;
  u32* cnt = cnt_ + gid * 128;              // 512 B stride per group
  u32* hb  = hbufbase + (size_t)gid * 8192; // 2 bufs x 16x256 u32

  // --- weights into VGPRs (held for all steps) ---
  u16x8 wf[3][8];
  #pragma unroll
  for (int kk = 0; kk < 8; ++kk){
    const int ks = half*8 + kk;
    #pragma unroll
    for (int g = 0; g < 3; ++g){
      const int nt = g*32 + s*4 + igrp;
      wf[g][kk] = *(const u16x8*)(frag + (((size_t)ks*96 + nt)*64 + lane)*8);
    }
  }
  // --- decoder-mode per-lane gi weights (z is rank 3) ---
  float wz[3][3] = {{0,0,0},{0,0,0},{0,0,0}}, wb[3] = {0,0,0};
  if (!gix && col < 500){
    #pragma unroll
    for (int g = 0; g < 3; ++g){
      #pragma unroll
      for (int k = 0; k < 3; ++k) wz[g][k] = Wih3[(g*500 + col)*3 + k];
      wb[g] = bih3[g*500 + col];
    }
  }

  float hold[4] = {0.f, 0.f, 0.f, 0.f};
  u16 giv[3][4];
  u64 zv[4];
  if (half == 0){
    // h0 = 0 (+ col511 = 1.0), packed pairs, sc1 to IF
    u32 me = (col == 511) ? 0x3F80u : 0u;
    u32 pr = __shfl_xor(me, 1, 64);
    if (!(c & 1)){
      u32 val = me | (pr << 16);
      #pragma unroll
      for (int r = 0; r < 4; ++r)
        __hip_atomic_store(hb + (q*4+r)*256 + (col>>1), val,
                           __ATOMIC_RELAXED, __HIP_MEMORY_SCOPE_AGENT);
    }
    __atomic_signal_fence(__ATOMIC_SEQ_CST);
    __builtin_amdgcn_s_waitcnt(0);          // h0 stores acked at IF
    __atomic_signal_fence(__ATOMIC_SEQ_CST);
    if (lane == 0)
      __hip_atomic_fetch_add(cnt, 1u, __ATOMIC_RELAXED, __HIP_MEMORY_SCOPE_AGENT);
    // prefetch inputs for t=0
    if (gix){
      #pragma unroll
      for (int g = 0; g < 3; ++g)
        #pragma unroll
        for (int r = 0; r < 4; ++r)
          giv[g][r] = __builtin_nontemporal_load(
              gix + ((size_t)(b0 + q*4 + r)*100 + 0)*1536 + g*512 + col);
    } else {
      #pragma unroll
      for (int r = 0; r < 4; ++r)
        zv[r] = zsrc[(size_t)(b0 + q*4 + r)*100 + 0];
    }
  }

  #pragma unroll 1
  for (int t = 0; t < 100; ++t){
    {
      const u32 target = 32u*(u32)(t+1);
      int guard = 0;
      while (__hip_atomic_load(cnt, __ATOMIC_RELAXED, __HIP_MEMORY_SCOPE_AGENT) < target){
        __builtin_amdgcn_s_sleep(1);
        if (++guard > (1<<22)) break;       // hang-breaker
      }
    }
    const u64* cur64 = (const u64*)(hb + (t & 1)*4096);
    u32*       nxt   = hb + ((t+1) & 1)*4096;

    f32x4 acc0 = zero4(), acc1 = zero4(), acc2 = zero4();
    #pragma unroll
    for (int kk = 0; kk < 8; ++kk){
      const int ks = half*8 + kk;
      const u64* p = cur64 + c*128 + ks*8 + q*2;
      u64pair pp;
      pp.a = __hip_atomic_load(p,     __ATOMIC_RELAXED, __HIP_MEMORY_SCOPE_AGENT);
      pp.b = __hip_atomic_load(p + 1, __ATOMIC_RELAXED, __HIP_MEMORY_SCOPE_AGENT);
      bf16x8 af = __builtin_bit_cast(bf16x8, pp);
      acc0 = MFMA16x16(af, __builtin_bit_cast(bf16x8, wf[0][kk]), acc0);
      acc1 = MFMA16x16(af, __builtin_bit_cast(bf16x8, wf[1][kk]), acc1);
      acc2 = MFMA16x16(af, __builtin_bit_cast(bf16x8, wf[2][kk]), acc2);
    }
    if (half == 1){
      red[(igrp*3 + 0)*64 + lane] = acc0;
      red[(igrp*3 + 1)*64 + lane] = acc1;
      red[(igrp*3 + 2)*64 + lane] = acc2;
    }
    __syncthreads();                        // the ONE barrier per step
    if (half == 0){
      const f32x4 p0 = red[(igrp*3+0)*64 + lane];
      const f32x4 p1 = red[(igrp*3+1)*64 + lane];
      const f32x4 p2 = red[(igrp*3+2)*64 + lane];
      u16 hvv[4];
      #pragma unroll
      for (int r = 0; r < 4; ++r){
        float gr, gz, gn;
        if (gix){
          gr = bf2f(giv[0][r]); gz = bf2f(giv[1][r]); gn = bf2f(giv[2][r]);
        } else {
          float z0 = bf2f((u16)(zv[r]));
          float z1 = bf2f((u16)(zv[r] >> 16));
          float z2 = bf2f((u16)(zv[r] >> 32));
          gr = z0*wz[0][0] + z1*wz[0][1] + z2*wz[0][2] + wb[0];
          gz = z0*wz[1][0] + z1*wz[1][1] + z2*wz[1][2] + wb[1];
          gn = z0*wz[2][0] + z1*wz[2][1] + z2*wz[2][2] + wb[2];
        }
        float ar = acc0[r] + p0[r] + gr;
        float az = acc1[r] + p1[r] + gz;
        float an = acc2[r] + p2[r];
        float rr = fast_sigmoid(ar);
        float zz = fast_sigmoid(az);
        float nn = fast_tanh(gn + rr*an);
        float h  = (1.f - zz)*nn + zz*hold[r];
        hold[r] = h;
        u16 hv16 = (col < 500) ? f2bf(h) : ((col == 511) ? (u16)0x3F80 : (u16)0);
        hvv[r] = hv16;
        u32 me = hv16;
        u32 pr = __shfl_xor(me, 1, 64);
        if (!(c & 1))
          __hip_atomic_store(nxt + (q*4+r)*256 + (col>>1), me | (pr << 16),
                             __ATOMIC_RELAXED, __HIP_MEMORY_SCOPE_AGENT);
      }
      __atomic_signal_fence(__ATOMIC_SEQ_CST);
      __builtin_amdgcn_s_waitcnt(0);        // h stores acked at IF
      __atomic_signal_fence(__ATOMIC_SEQ_CST);
      if (lane == 0)
        __hip_atomic_fetch_add(cnt, 1u, __ATOMIC_RELAXED, __HIP_MEMORY_SCOPE_AGENT);
      #pragma unroll
      for (int r = 0; r < 4; ++r)
        __builtin_nontemporal_store(hvv[r],
            hout + ((size_t)(b0 + q*4 + r)*100 + t)*512 + col);
      if (t < 99){
        if (gix){
          #pragma unroll
          for (int g = 0; g < 3; ++g)
            #pragma unroll
            for (int r = 0; r < 4; ++r)
              giv[g][r] = __builtin_nontemporal_load(
                  gix + ((size_t)(b0 + q*4 + r)*100 + (t+1))*1536 + g*512 + col);
        } else {
          #pragma unroll
          for (int r = 0; r < 4; ++r)
            zv[r] = zsrc[(size_t)(b0 + q*4 + r)*100 + (t+1)];
        }
      }
    }
  }
}

// ---------------------------------------------------------------------------
// Fused post-net chain: P1 = lrelu(A@fA), P2 = lrelu(P1@fB), then
// mode 0: hm[51200][8] = P2 @ ZFR   mode 1: heads (mu, softplus std).
// C-layout -> A-layout transform through a 64 KB LDS tile between stages.
// Block = 64 rows, 8 waves = 4 row-tiles x 2 col-halves.
// ---------------------------------------------------------------------------
__global__ __launch_bounds__(512, 4) void post_chain(
    const u16* __restrict__ A, const u16* __restrict__ fA,
    const u16* __restrict__ fB, const u16* __restrict__ f3,
    float* __restrict__ o0, float* __restrict__ o1, int mode)
{
  __shared__ u16 AS[32768];                 // [rt4][ks16][qq4][m16][j8]
  const int tid = threadIdx.x, lane = tid & 63, w = tid >> 6;
  const int q = lane >> 4, c = lane & 15;
  const int rt = w & 3, nh = w >> 2;
  const size_t rowbase = (size_t)blockIdx.x * 64;

  // ---- stage 1: P1 tile from global A ----
  f32x4 acc[16];
  #pragma unroll
  for (int i = 0; i < 16; ++i) acc[i] = zero4();
  {
    const u16* Ar = A + (rowbase + rt*16 + c) * 512 + q * 8;
    #pragma unroll 1
    for (int ks = 0; ks < 16; ++ks){
      bf16x8 af = __builtin_bit_cast(bf16x8, *(const u16x8*)(Ar + ks * 32));
      #pragma unroll
      for (int i = 0; i < 16; ++i){
        const int nt = nh * 16 + i;
        bf16x8 bf = __builtin_bit_cast(bf16x8,
            *(const u16x8*)(fA + (((size_t)ks * 32 + nt) * 64 + lane) * 8));
        acc[i] = MFMA16x16(af, bf, acc[i]);
      }
    }
  }
  #pragma unroll
  for (int i = 0; i < 16; ++i){
    const int cl = (nh * 16 + i) * 16 + c;
    const int ks2 = cl >> 5, qq = (cl >> 3) & 3, j = cl & 7;
    #pragma unroll
    for (int r = 0; r < 4; ++r){
      const int m = q*4 + r;
      float v = acc[i][r];
      v = fmaxf(v, 0.1f * v);
      AS[(((rt*16 + ks2)*4 + qq)*16 + m)*8 + j] =
          (cl < 500) ? f2bf(v) : ((cl == 511) ? (u16)0x3F80 : (u16)0);
    }
  }
  __syncthreads();

  // ---- stage 2: P2 = lrelu(P1@fB), P1 read from LDS in A-frag order ----
  #pragma unroll
  for (int i = 0; i < 16; ++i) acc[i] = zero4();
  #pragma unroll 1
  for (int ks = 0; ks < 16; ++ks){
    bf16x8 af = __builtin_bit_cast(bf16x8,
        *(const u16x8*)&AS[(((rt*16 + ks)*4 + q)*16 + c)*8]);
    #pragma unroll
    for (int i = 0; i < 16; ++i){
      const int nt = nh * 16 + i;
      bf16x8 bf = __builtin_bit_cast(bf16x8,
          *(const u16x8*)(fB + (((size_t)ks * 32 + nt) * 64 + lane) * 8));
      acc[i] = MFMA16x16(af, bf, acc[i]);
    }
  }
  __syncthreads();                          // all stage-2 reads done
  #pragma unroll
  for (int i = 0; i < 16; ++i){
    const int cl = (nh * 16 + i) * 16 + c;
    const int ks2 = cl >> 5, qq = (cl >> 3) & 3, j = cl & 7;
    #pragma unroll
    for (int r = 0; r < 4; ++r){
      const int m = q*4 + r;
      float v = acc[i][r];
      v = fmaxf(v, 0.1f * v);
      AS[(((rt*16 + ks2)*4 + qq)*16 + m)*8 + j] =
          (cl < 500) ? f2bf(v) : ((cl == 511) ? (u16)0x3F80 : (u16)0);
    }
  }
  __syncthreads();

  // ---- stage 3 ----
  if (mode == 0){
    if (w < 4){
      const int rt3 = w;
      f32x4 a3 = zero4();
      #pragma unroll 1
      for (int ks = 0; ks < 16; ++ks){
        bf16x8 af = __builtin_bit_cast(bf16x8,
            *(const u16x8*)&AS[(((rt3*16 + ks)*4 + q)*16 + c)*8]);
        bf16x8 bf = __builtin_bit_cast(bf16x8,
            *(const u16x8*)(f3 + (((size_t)ks * 64) + lane) * 8));
        a3 = MFMA16x16(af, bf, a3);
      }
      if (c < 6){
        #pragma unroll
        for (int r = 0; r < 4; ++r)
          o0[(rowbase + rt3*16 + q*4 + r)*8 + c] = a3[r];
      }
    }
  } else {
    const int rt3 = w & 3, hh = w >> 2;
    f32x4 a3[3];
    #pragma unroll
    for (int ii = 0; ii < 3; ++ii) a3[ii] = zero4();
    #pragma unroll 1
    for (int ks = 0; ks < 16; ++ks){
      bf16x8 af = __builtin_bit_cast(bf16x8,
          *(const u16x8*)&AS[(((rt3*16 + ks)*4 + q)*16 + c)*8]);
      #pragma unroll
      for (int ii = 0; ii < 3; ++ii){
        const int nt = hh*3 + ii;
        bf16x8 bf = __builtin_bit_cast(bf16x8,
            *(const u16x8*)(f3 + (((size_t)ks * 6 + nt) * 64 + lane) * 8));
        a3[ii] = MFMA16x16(af, bf, a3[ii]);
      }
    }
    #pragma unroll
    for (int ii = 0; ii < 3; ++ii){
      const int cc = (hh*3 + ii)*16 + c;
      const int grp = cc / 48;
      const int cl = cc - grp * 48;
      if (cl < 38){
        #pragma unroll
        for (int r = 0; r < 4; ++r){
          const size_t row = rowbase + rt3*16 + q*4 + r;
          if (grp == 0) o0[row*38 + cl] = a3[ii][r];
          else          o1[row*38 + cl] = fast_softplus(a3[ii][r]) + 1e-4f;
        }
      }
    }
  }
}

// ---------------------------------------------------------------------------
// Sequential latent scan: only the 3x3 z-feedback part (h-part precomputed).
// ---------------------------------------------------------------------------
__global__ void scan_kernel(const float* __restrict__ hm, const float* __restrict__ eps,
                            const float* __restrict__ zmW, const float* __restrict__ zsW,
                            float* __restrict__ zgen, float* __restrict__ zmu,
                            float* __restrict__ zstd)
{
  int b = blockIdx.x * blockDim.x + threadIdx.x;
  if (b >= 512) return;
  float Wm[3][3], Ws[3][3];
  #pragma unroll
  for (int j = 0; j < 3; ++j)
    #pragma unroll
    for (int k = 0; k < 3; ++k){
      Wm[j][k] = zmW[j * 503 + 500 + k];
      Ws[j][k] = zsW[j * 503 + 500 + k];
    }
  float z0 = 0.f, z1 = 0.f, z2 = 0.f;
  for (int t = 0; t < 100; ++t){
    size_t row = (size_t)b * 100 + t;
    const float* h = hm + row * 8;
    const float* e = eps + row * 3;
    float zn[3];
    #pragma unroll
    for (int j = 0; j < 3; ++j){
      float m_ = h[j]     + Wm[j][0]*z0 + Wm[j][1]*z1 + Wm[j][2]*z2;
      float p_ = h[3 + j] + Ws[j][0]*z0 + Ws[j][1]*z1 + Ws[j][2]*z2;
      float s_ = fast_softplus(p_) + 1e-4f;
      float zv = m_ + s_ * e[j];
      zgen[row * 3 + j] = zv;
      zmu [row * 3 + j] = m_;
      zstd[row * 3 + j] = s_;
      zn[j] = zv;
    }
    z0 = zn[0]; z1 = zn[1]; z2 = zn[2];
  }
}

// ---------------------------------------------------------------------------
// Planar flow (parallel over 51200); also emits packed bf16 z for dec GRU.
// ---------------------------------------------------------------------------
__global__ void flow_kernel(const float* __restrict__ zgen, const float* __restrict__ fp,
                            float* __restrict__ zfin, float* __restrict__ ldj,
                            u16* __restrict__ zf16)
{
  int idx = blockIdx.x * blockDim.x + threadIdx.x;
  if (idx >= 51200) return;
  float z0 = zgen[idx*3+0], z1 = zgen[idx*3+1], z2 = zgen[idx*3+2];
  float ld = 0.f;
  #pragma unroll 1
  for (int l = 0; l < 20; ++l){
    const float* p = fp + l * 8;
    float lin = z0*p[0] + z1*p[1] + z2*p[2] + p[3];
    float tt = fast_tanh(lin);
    z0 += p[4]*tt; z1 += p[5]*tt; z2 += p[6]*tt;
    float det = 1.f + (1.f - tt*tt) * p[7];
    ld += __logf(fabsf(det) + 1e-7f);
  }
  zfin[idx*3+0] = z0; zfin[idx*3+1] = z1; zfin[idx*3+2] = z2;
  ldj[idx] = ld;
  u16x4 o; o[0] = f2bf(z0); o[1] = f2bf(z1); o[2] = f2bf(z2); o[3] = 0x3F80;
  *(u16x4*)(zf16 + (size_t)idx * 4) = o;
}

// ---------------------------------------------------------------------------
extern "C" void kernel_launch(void* const* d_in, const int* in_sizes, int n_in,
                              void* d_out, int out_size, void* d_ws, size_t ws_size,
                              hipStream_t stream)
{
  const float* x       = (const float*)d_in[0];
  const float* eps     = (const float*)d_in[1];
  const float* enc_Wih = (const float*)d_in[2];
  const float* enc_Whh = (const float*)d_in[3];
  const float* enc_bih = (const float*)d_in[4];
  const float* enc_bhh = (const float*)d_in[5];
  const float* enc_W1  = (const float*)d_in[6];
  const float* enc_b1  = (const float*)d_in[7];
  const float* enc_W2  = (const float*)d_in[8];
  const float* enc_b2  = (const float*)d_in[9];
  const float* zm_W    = (const float*)d_in[10];
  const float* zm_b    = (const float*)d_in[11];
  const float* zs_W    = (const float*)d_in[12];
  const float* zs_b    = (const float*)d_in[13];
  const float* flow_w  = (const float*)d_in[14];
  const float* flow_b  = (const float*)d_in[15];
  const float* flow_u  = (const float*)d_in[16];
  const float* dec_Wih = (const float*)d_in[17];
  const float* dec_Whh = (const float*)d_in[18];
  const float* dec_bih = (const float*)d_in[19];
  const float* dec_bhh = (const float*)d_in[20];
  const float* dec_W1  = (const float*)d_in[21];
  const float* dec_b1  = (const float*)d_in[22];
  const float* dec_W2  = (const float*)d_in[23];
  const float* dec_b2  = (const float*)d_in[24];
  const float* xm_W    = (const float*)d_in[25];
  const float* xm_b    = (const float*)d_in[26];
  const float* xs_W    = (const float*)d_in[27];
  const float* xs_b    = (const float*)d_in[28];
  (void)in_sizes; (void)n_in; (void)out_size; (void)ws_size;

  float* out    = (float*)d_out;
  float* r_mu   = out;                 // [512,100,38]
  float* r_std  = out + 1945600;       // [512,100,38]
  float* r_zgen = out + 3891200;       // [512,100,3]
  float* r_zfin = out + 4044800;       // [512,100,3]
  float* r_zmu  = out + 4198400;       // [512,100,3]
  float* r_zstd = out + 4352000;       // [512,100,3]
  float* r_ldj  = out + 4505600;       // [512,100,1]

  char* ws = (char*)d_ws;
  size_t off = 0;
  auto alloc = [&](size_t bytes)->char*{
    char* p = ws + off;
    off += (bytes + 255) & ~(size_t)255;
    return p;
  };
  u16* H1    = (u16*)alloc((size_t)51200*512*2);     // GRU hidden states
  u16* BIG   = (u16*)alloc((size_t)51200*1536*2);    // enc gi buffer
  u16* ENCF  = (u16*)alloc((size_t)16*96*512*2);
  u16* DECF  = (u16*)alloc((size_t)16*96*512*2);
  u16* EGIF  = (u16*)alloc((size_t)2*96*512*2);
  u16* PF0   = (u16*)alloc((size_t)16*32*512*2);
  u16* PF1   = (u16*)alloc((size_t)16*32*512*2);
  u16* PF2   = (u16*)alloc((size_t)16*32*512*2);
  u16* PF3   = (u16*)alloc((size_t)16*32*512*2);
  u16* ZFR   = (u16*)alloc((size_t)16*1*512*2);
  u16* HFR   = (u16*)alloc((size_t)16*6*512*2);
  float* FPP = (float*)alloc((size_t)20*8*4);
  float* HM  = (float*)alloc((size_t)51200*8*4);
  u16* ZF16  = (u16*)alloc((size_t)51200*4*2);
  u32* HBUF  = (u32*)alloc((size_t)32*2*16*512*2);   // h exchange (packed bf16 pairs)
  u32* CNT   = (u32*)alloc((size_t)2*32*128*4);      // 512 B/group counters, enc+dec

  hipMemsetAsync(CNT, 0, 2*32*128*4, stream);
  build_all<<<10849,256,0,stream>>>(ENCF,DECF,EGIF,PF0,PF1,PF2,PF3,ZFR,HFR,FPP,
      enc_Whh,enc_bhh,enc_Wih,dec_Whh,dec_bhh,
      enc_W1,enc_b1,enc_W2,enc_b2,dec_W1,dec_b1,dec_W2,dec_b2,
      zm_W,zm_b,zs_W,zs_b,xm_W,xm_b,xs_W,xs_b,flow_w,flow_b,flow_u);

  // --- encoder ---
  gi_enc_kernel<<<1600,512,0,stream>>>(x, EGIF, enc_bih, BIG);
  gru3_kernel<<<256,512,0,stream>>>(ENCF, BIG, nullptr, nullptr, nullptr,
                                    HBUF, H1, CNT);
  post_chain<<<800,512,0,stream>>>(H1, PF0, PF1, ZFR, HM, nullptr, 0);

  // --- latent scan + planar flow ---
  scan_kernel<<<2,256,0,stream>>>(HM, eps, zm_W, zs_W, r_zgen, r_zmu, r_zstd);
  flow_kernel<<<200,256,0,stream>>>(r_zgen, FPP, r_zfin, r_ldj, ZF16);

  // --- decoder ---
  gru3_kernel<<<256,512,0,stream>>>(DECF, nullptr, (const u64*)ZF16,
                                    dec_Wih, dec_bih, HBUF, H1, CNT + 32*128);
  post_chain<<<800,512,0,stream>>>(H1, PF2, PF3, HFR, r_mu, r_std, 1);
}

// Round 5
// 1923.441 us; speedup vs baseline: 1.1961x; 1.1961x over previous
//
#include <hip/hip_runtime.h>

typedef unsigned short u16;
typedef unsigned int u32;
typedef unsigned long long u64;
typedef __bf16 bf16x8 __attribute__((ext_vector_type(8)));
typedef float f32x4 __attribute__((ext_vector_type(4)));
typedef u16 u16x8 __attribute__((ext_vector_type(8)));
typedef u16 u16x4 __attribute__((ext_vector_type(4)));

struct u64pair { u64 a, b; };

#define MFMA16x16(a,b,c) __builtin_amdgcn_mfma_f32_16x16x32_bf16((a),(b),(c),0,0,0)

static __device__ __forceinline__ u16 f2bf(float f){
  u32 u = __builtin_bit_cast(u32, f);
  u += 0x7fffu + ((u >> 16) & 1u);
  return (u16)(u >> 16);
}
static __device__ __forceinline__ float bf2f(u16 h){
  u32 u = ((u32)h) << 16;
  return __builtin_bit_cast(float, u);
}
static __device__ __forceinline__ float fast_sigmoid(float x){
  return 1.f / (1.f + __expf(-x));
}
static __device__ __forceinline__ float fast_tanh(float x){
  float e = __expf(2.f * x);
  return 1.f - 2.f / (e + 1.f);
}
static __device__ __forceinline__ float fast_softplus(float x){
  return (x > 15.f) ? x : __logf(1.f + __expf(x));
}
static __device__ __forceinline__ f32x4 zero4(){
  f32x4 v; v[0]=0.f; v[1]=0.f; v[2]=0.f; v[3]=0.f; return v;
}

// ---------------------------------------------------------------------------
// Weight swizzle into MFMA B-fragment order:
// dst[ks][nt][lane][j] = W[k = ks*32 + (lane>>4)*8 + j][ncol = nt*16 + (lane&15)]
// modes: 0 GRU hidden  2 post(500x500+b)  3 zW  4 heads  5 enc Wih
// ---------------------------------------------------------------------------
static __device__ __forceinline__ void build_one(
    u16* __restrict__ dst, int mode, int NT, int idx,
    const float* __restrict__ W0, const float* __restrict__ b0,
    const float* __restrict__ W1, const float* __restrict__ b1)
{
  int j    = idx & 7;
  int lane = (idx >> 3) & 63;
  int ntks = idx >> 9;
  int nt   = ntks % NT;
  int ks   = ntks / NT;
  int k    = ks * 32 + ((lane >> 4) << 3) + j;
  int ncol = (nt << 4) + (lane & 15);
  float v = 0.f;
  if (mode == 0){                         // GRU hidden: rows 0..499 Whh^T, 511 bhh
    int g = ncol >> 9;
    int jin = ncol & 511;
    if (jin < 500){
      int row = g * 500 + jin;
      if (k < 500) v = W0[row * 500 + k];
      else if (k == 511) v = b0[row];
    }
  } else if (mode == 2){                  // post: W0 [500][500], bias row 511
    if (ncol < 500){
      if (k < 500) v = W0[ncol * 500 + k];
      else if (k == 511) v = b0[ncol];
    }
  } else if (mode == 3){                  // zW: cols 0..2 zm (W0 [3][503]), 3..5 zs
    int c = ncol;
    if (c < 3){
      if (k < 500) v = W0[c * 503 + k];
      else if (k == 511) v = b0[c];
    } else if (c < 6){
      int cc = c - 3;
      if (k < 500) v = W1[cc * 503 + k];
      else if (k == 511) v = b1[cc];
    }
  } else if (mode == 4){                  // heads: cols 0..47 xm (<38), 48..95 xs
    int grp = ncol / 48;
    int cc  = ncol - grp * 48;
    if (grp < 2 && cc < 38){
      const float* W  = grp ? W1 : W0;
      const float* bb = grp ? b1 : b0;
      if (k < 500) v = W[cc * 500 + k];
      else if (k == 511) v = bb[cc];
    }
  } else {                                // mode 5: enc Wih [1500][38]
    int g = ncol >> 9;
    int jin = ncol & 511;
    if (jin < 500 && k < 38) v = W0[(g * 500 + jin) * 38 + k];
  }
  dst[idx] = f2bf(v);
}

// One launch for all weight prep + flow param precompute.
__global__ void build_all(
    u16* ENCF, u16* DECF, u16* EGIF, u16* PF0, u16* PF1, u16* PF2, u16* PF3,
    u16* ZFR, u16* HFR, float* FPP,
    const float* enc_Whh, const float* enc_bhh, const float* enc_Wih,
    const float* dec_Whh, const float* dec_bhh,
    const float* enc_W1, const float* enc_b1, const float* enc_W2, const float* enc_b2,
    const float* dec_W1, const float* dec_b1, const float* dec_W2, const float* dec_b2,
    const float* zm_W, const float* zm_b, const float* zs_W, const float* zs_b,
    const float* xm_W, const float* xm_b, const float* xs_W, const float* xs_b,
    const float* flow_w, const float* flow_b, const float* flow_u)
{
  const int b = blockIdx.x, tid = threadIdx.x;
  if      (b < 3072)  build_one(ENCF,0,96,(b       )*256+tid, enc_Whh,enc_bhh,0,0);
  else if (b < 6144)  build_one(DECF,0,96,(b- 3072 )*256+tid, dec_Whh,dec_bhh,0,0);
  else if (b < 6528)  build_one(EGIF,5,96,(b- 6144 )*256+tid, enc_Wih,0,0,0);
  else if (b < 7552)  build_one(PF0 ,2,32,(b- 6528 )*256+tid, enc_W1,enc_b1,0,0);
  else if (b < 8576)  build_one(PF1 ,2,32,(b- 7552 )*256+tid, enc_W2,enc_b2,0,0);
  else if (b < 9600)  build_one(PF2 ,2,32,(b- 8576 )*256+tid, dec_W1,dec_b1,0,0);
  else if (b < 10624) build_one(PF3 ,2,32,(b- 9600 )*256+tid, dec_W2,dec_b2,0,0);
  else if (b < 10656) build_one(ZFR ,3, 1,(b-10624 )*256+tid, zm_W,zm_b,zs_W,zs_b);
  else if (b < 10848) build_one(HFR ,4, 6,(b-10656 )*256+tid, xm_W,xm_b,xs_W,xs_b);
  else if (tid < 20){
    int l = tid;
    float w0 = flow_w[l*3+0], w1 = flow_w[l*3+1], w2 = flow_w[l*3+2];
    float u0 = flow_u[l*3+0], u1 = flow_u[l*3+1], u2 = flow_u[l*3+2];
    float wu = w0*u0 + w1*u1 + w2*u2;
    float m  = -1.f + fast_softplus(wu);
    float ww = w0*w0 + w1*w1 + w2*w2 + 1e-7f;
    float sc = (m - wu) / ww;
    float uh0 = u0 + sc*w0, uh1 = u1 + sc*w1, uh2 = u2 + sc*w2;
    float uw  = uh0*w0 + uh1*w1 + uh2*w2;
    FPP[l*8+0]=w0; FPP[l*8+1]=w1; FPP[l*8+2]=w2; FPP[l*8+3]=flow_b[l];
    FPP[l*8+4]=uh0; FPP[l*8+5]=uh1; FPP[l*8+6]=uh2; FPP[l*8+7]=uw;
  }
}

// ---------------------------------------------------------------------------
// Encoder input-gates precompute: gi[51200][1536] = x[51200][38] @ Wih^T + bih
// ---------------------------------------------------------------------------
__global__ __launch_bounds__(512, 2) void gi_enc_kernel(
    const float* __restrict__ x, const u16* __restrict__ frag2,
    const float* __restrict__ bih, u16* __restrict__ gi)
{
  const int tid = threadIdx.x, lane = tid & 63, v = tid >> 6;
  const int q = lane >> 4, c = lane & 15;
  const size_t rowbase = (size_t)blockIdx.x * 32;
  u16 a[2][2][8];
  #pragma unroll
  for (int tile = 0; tile < 2; ++tile){
    const float* xr = x + (rowbase + tile*16 + c) * 38;
    #pragma unroll
    for (int j = 0; j < 8; ++j){
      int k0 = q*8 + j;
      a[tile][0][j] = f2bf(xr[k0]);
      int k1 = 32 + q*8 + j;
      a[tile][1][j] = (k1 < 38) ? f2bf(xr[k1]) : (u16)0;
    }
  }
  f32x4 acc[2][12];
  #pragma unroll
  for (int tile = 0; tile < 2; ++tile)
    #pragma unroll
    for (int i = 0; i < 12; ++i) acc[tile][i] = zero4();
  #pragma unroll
  for (int i = 0; i < 12; ++i){
    const int nt = v*12 + i;
    bf16x8 b0 = __builtin_bit_cast(bf16x8,
        *(const u16x8*)(frag2 + (((size_t)0*96 + nt)*64 + lane)*8));
    bf16x8 b1 = __builtin_bit_cast(bf16x8,
        *(const u16x8*)(frag2 + (((size_t)1*96 + nt)*64 + lane)*8));
    #pragma unroll
    for (int tile = 0; tile < 2; ++tile){
      bf16x8 a0 = __builtin_bit_cast(bf16x8, *(const u16x8*)a[tile][0]);
      bf16x8 a1 = __builtin_bit_cast(bf16x8, *(const u16x8*)a[tile][1]);
      acc[tile][i] = MFMA16x16(a0, b0, acc[tile][i]);
      acc[tile][i] = MFMA16x16(a1, b1, acc[tile][i]);
    }
  }
  #pragma unroll
  for (int i = 0; i < 12; ++i){
    const int nt = v*12 + i;
    const int ncol = nt*16 + c;
    const int g = ncol >> 9, jin = ncol & 511;
    const float bias = (jin < 500) ? bih[g*500 + jin] : 0.f;
    #pragma unroll
    for (int tile = 0; tile < 2; ++tile)
      #pragma unroll
      for (int r = 0; r < 4; ++r){
        size_t row = rowbase + tile*16 + q*4 + r;
        gi[row*1536 + ncol] = f2bf(acc[tile][i][r] + bias);
      }
  }
}

// ---------------------------------------------------------------------------
// Register-resident cooperative GRU, v4: flag-array sync, NO atomics.
// Grid 256 = 32 batch-groups x 8 col-slices; 8 waves = 4 nt x 2 K-halves.
// Per group: 32 flags (one per writer wave, 1-2 lines). Writer wave: nxt
// stores (sc1) -> s_waitcnt(0) -> plain sc1 store of t+2 to OWN flag (no RMW
// serialization; IF is memory-side, plain same-line stores pipeline).
// Poller = wave 4 (half-1, idle during epilogue -> detect overlaps epilogue):
// lanes 0..31 load the 32 flags in ONE instruction, __ballot(f>=target).
// 2 barriers/step. Safety: flag=t+2 implies that block finished ALL step-t
// h-reads (stores happen after its reduce barrier), so buffer reuse at t+2
// cannot race a straggler.
// enc: gi streamed. dec: gi on the fly from z (rank 3).
// 84 KB LDS forces 1 block/CU -> 256 blocks co-resident.
// ---------------------------------------------------------------------------
__global__ __launch_bounds__(512, 2) void gru4_kernel(
    const u16* __restrict__ frag, const u16* __restrict__ gix,
    const u64* __restrict__ zsrc, const float* __restrict__ Wih3,
    const float* __restrict__ bih3,
    u32* __restrict__ hbufbase, u16* __restrict__ hout, u32* __restrict__ flags_)
{
  __shared__ f32x4 red[5376];               // 86016 B: forces 1 block/CU
  const int tid  = threadIdx.x, lane = tid & 63;
  const int wv   = tid >> 6, igrp = wv & 3, half = wv >> 2;
  const int q    = lane >> 4, c = lane & 15;
  const int gid  = blockIdx.x & 31, s = blockIdx.x >> 5;
  const int b0   = gid * 16;
  const int col  = (s*4 + igrp)*16 + c;
  u32* flags = flags_ + gid * 128;          // 512 B stride; first 32 used
  u32* hb  = hbufbase + (size_t)gid * 8192; // 2 bufs x 16x256 u32

  // --- weights into VGPRs (held for all steps) ---
  u16x8 wf[3][8];
  #pragma unroll
  for (int kk = 0; kk < 8; ++kk){
    const int ks = half*8 + kk;
    #pragma unroll
    for (int g = 0; g < 3; ++g){
      const int nt = g*32 + s*4 + igrp;
      wf[g][kk] = *(const u16x8*)(frag + (((size_t)ks*96 + nt)*64 + lane)*8);
    }
  }
  // --- decoder-mode per-lane gi weights (z is rank 3) ---
  float wz[3][3] = {{0,0,0},{0,0,0},{0,0,0}}, wb[3] = {0,0,0};
  if (!gix && col < 500){
    #pragma unroll
    for (int g = 0; g < 3; ++g){
      #pragma unroll
      for (int k = 0; k < 3; ++k) wz[g][k] = Wih3[(g*500 + col)*3 + k];
      wb[g] = bih3[g*500 + col];
    }
  }

  float hold[4] = {0.f, 0.f, 0.f, 0.f};
  u16 giv[3][4];
  u64 zv[4];
  if (half == 0){
    // h0 = 0 (+ col511 = 1.0), packed pairs, sc1 to IF
    u32 me = (col == 511) ? 0x3F80u : 0u;
    u32 pr = __shfl_xor(me, 1, 64);
    if (!(c & 1)){
      u32 val = me | (pr << 16);
      #pragma unroll
      for (int r = 0; r < 4; ++r)
        __hip_atomic_store(hb + (q*4+r)*256 + (col>>1), val,
                           __ATOMIC_RELAXED, __HIP_MEMORY_SCOPE_AGENT);
    }
    __atomic_signal_fence(__ATOMIC_SEQ_CST);
    __builtin_amdgcn_s_waitcnt(0);          // h0 stores acked at IF
    __atomic_signal_fence(__ATOMIC_SEQ_CST);
    if (lane == 0)
      __hip_atomic_store(flags + s*4 + igrp, 1u,
                         __ATOMIC_RELAXED, __HIP_MEMORY_SCOPE_AGENT);
    // prefetch inputs for t=0
    if (gix){
      #pragma unroll
      for (int g = 0; g < 3; ++g)
        #pragma unroll
        for (int r = 0; r < 4; ++r)
          giv[g][r] = __builtin_nontemporal_load(
              gix + ((size_t)(b0 + q*4 + r)*100 + 0)*1536 + g*512 + col);
    } else {
      #pragma unroll
      for (int r = 0; r < 4; ++r)
        zv[r] = zsrc[(size_t)(b0 + q*4 + r)*100 + 0];
    }
  }

  #pragma unroll 1
  for (int t = 0; t < 100; ++t){
    if (wv == 4){                           // poller: half-1 wave, overlaps epilogue
      const u32 target = (u32)(t + 1);
      int guard = 0;
      for (;;){
        u32 f = __hip_atomic_load(flags + (lane & 31),
                                  __ATOMIC_RELAXED, __HIP_MEMORY_SCOPE_AGENT);
        if (__ballot(f >= target) == ~0ull) break;
        if (++guard > (1<<20)) break;       // hang-breaker
      }
    }
    __syncthreads();                        // barrier 1: h_t visible to all
    const u64* cur64 = (const u64*)(hb + (t & 1)*4096);
    u32*       nxt   = hb + ((t+1) & 1)*4096;

    f32x4 acc0 = zero4(), acc1 = zero4(), acc2 = zero4();
    #pragma unroll
    for (int kk = 0; kk < 8; ++kk){
      const int ks = half*8 + kk;
      const u64* p = cur64 + c*128 + ks*8 + q*2;
      u64pair pp;
      pp.a = __hip_atomic_load(p,     __ATOMIC_RELAXED, __HIP_MEMORY_SCOPE_AGENT);
      pp.b = __hip_atomic_load(p + 1, __ATOMIC_RELAXED, __HIP_MEMORY_SCOPE_AGENT);
      bf16x8 af = __builtin_bit_cast(bf16x8, pp);
      acc0 = MFMA16x16(af, __builtin_bit_cast(bf16x8, wf[0][kk]), acc0);
      acc1 = MFMA16x16(af, __builtin_bit_cast(bf16x8, wf[1][kk]), acc1);
      acc2 = MFMA16x16(af, __builtin_bit_cast(bf16x8, wf[2][kk]), acc2);
    }
    if (half == 1){
      red[(igrp*3 + 0)*64 + lane] = acc0;
      red[(igrp*3 + 1)*64 + lane] = acc1;
      red[(igrp*3 + 2)*64 + lane] = acc2;
    }
    __syncthreads();                        // barrier 2: partials in LDS
    if (half == 0){
      const f32x4 p0 = red[(igrp*3+0)*64 + lane];
      const f32x4 p1 = red[(igrp*3+1)*64 + lane];
      const f32x4 p2 = red[(igrp*3+2)*64 + lane];
      u16 hvv[4];
      #pragma unroll
      for (int r = 0; r < 4; ++r){
        float gr, gz, gn;
        if (gix){
          gr = bf2f(giv[0][r]); gz = bf2f(giv[1][r]); gn = bf2f(giv[2][r]);
        } else {
          float z0 = bf2f((u16)(zv[r]));
          float z1 = bf2f((u16)(zv[r] >> 16));
          float z2 = bf2f((u16)(zv[r] >> 32));
          gr = z0*wz[0][0] + z1*wz[0][1] + z2*wz[0][2] + wb[0];
          gz = z0*wz[1][0] + z1*wz[1][1] + z2*wz[1][2] + wb[1];
          gn = z0*wz[2][0] + z1*wz[2][1] + z2*wz[2][2] + wb[2];
        }
        float ar = acc0[r] + p0[r] + gr;
        float az = acc1[r] + p1[r] + gz;
        float an = acc2[r] + p2[r];
        float rr = fast_sigmoid(ar);
        float zz = fast_sigmoid(az);
        float nn = fast_tanh(gn + rr*an);
        float h  = (1.f - zz)*nn + zz*hold[r];
        hold[r] = h;
        u16 hv16 = (col < 500) ? f2bf(h) : ((col == 511) ? (u16)0x3F80 : (u16)0);
        hvv[r] = hv16;
        u32 me = hv16;
        u32 pr = __shfl_xor(me, 1, 64);
        if (!(c & 1))
          __hip_atomic_store(nxt + (q*4+r)*256 + (col>>1), me | (pr << 16),
                             __ATOMIC_RELAXED, __HIP_MEMORY_SCOPE_AGENT);
      }
      __atomic_signal_fence(__ATOMIC_SEQ_CST);
      __builtin_amdgcn_s_waitcnt(0);        // nxt stores acked at IF
      __atomic_signal_fence(__ATOMIC_SEQ_CST);
      if (lane == 0)
        __hip_atomic_store(flags + s*4 + igrp, (u32)(t + 2),
                           __ATOMIC_RELAXED, __HIP_MEMORY_SCOPE_AGENT);
      // off-critical-path work after the signal
      #pragma unroll
      for (int r = 0; r < 4; ++r)
        __builtin_nontemporal_store(hvv[r],
            hout + ((size_t)(b0 + q*4 + r)*100 + t)*512 + col);
      if (t < 99){
        if (gix){
          #pragma unroll
          for (int g = 0; g < 3; ++g)
            #pragma unroll
            for (int r = 0; r < 4; ++r)
              giv[g][r] = __builtin_nontemporal_load(
                  gix + ((size_t)(b0 + q*4 + r)*100 + (t+1))*1536 + g*512 + col);
        } else {
          #pragma unroll
          for (int r = 0; r < 4; ++r)
            zv[r] = zsrc[(size_t)(b0 + q*4 + r)*100 + (t+1)];
        }
      }
    }
  }
}

// ---------------------------------------------------------------------------
// Fused post-net chain: P1 = lrelu(A@fA), P2 = lrelu(P1@fB), then
// mode 0: hm[51200][8] = P2 @ ZFR   mode 1: heads (mu, softplus std).
// C-layout -> A-layout transform through a 64 KB LDS tile between stages.
// LDS conflicts measured at the structural floor for distinct-data b128.
// ---------------------------------------------------------------------------
__global__ __launch_bounds__(512, 4) void post_chain(
    const u16* __restrict__ A, const u16* __restrict__ fA,
    const u16* __restrict__ fB, const u16* __restrict__ f3,
    float* __restrict__ o0, float* __restrict__ o1, int mode)
{
  __shared__ u16 AS[32768];                 // [rt4][ks16][qq4][m16][j8]
  const int tid = threadIdx.x, lane = tid & 63, w = tid >> 6;
  const int q = lane >> 4, c = lane & 15;
  const int rt = w & 3, nh = w >> 2;
  const size_t rowbase = (size_t)blockIdx.x * 64;

  // ---- stage 1: P1 tile from global A ----
  f32x4 acc[16];
  #pragma unroll
  for (int i = 0; i < 16; ++i) acc[i] = zero4();
  {
    const u16* Ar = A + (rowbase + rt*16 + c) * 512 + q * 8;
    #pragma unroll 1
    for (int ks = 0; ks < 16; ++ks){
      bf16x8 af = __builtin_bit_cast(bf16x8, *(const u16x8*)(Ar + ks * 32));
      #pragma unroll
      for (int i = 0; i < 16; ++i){
        const int nt = nh * 16 + i;
        bf16x8 bf = __builtin_bit_cast(bf16x8,
            *(const u16x8*)(fA + (((size_t)ks * 32 + nt) * 64 + lane) * 8));
        acc[i] = MFMA16x16(af, bf, acc[i]);
      }
    }
  }
  #pragma unroll
  for (int i = 0; i < 16; ++i){
    const int cl = (nh * 16 + i) * 16 + c;
    const int ks2 = cl >> 5, qq = (cl >> 3) & 3, j = cl & 7;
    #pragma unroll
    for (int r = 0; r < 4; ++r){
      const int m = q*4 + r;
      float v = acc[i][r];
      v = fmaxf(v, 0.1f * v);
      AS[(((rt*16 + ks2)*4 + qq)*16 + m)*8 + j] =
          (cl < 500) ? f2bf(v) : ((cl == 511) ? (u16)0x3F80 : (u16)0);
    }
  }
  __syncthreads();

  // ---- stage 2: P2 = lrelu(P1@fB), P1 read from LDS in A-frag order ----
  #pragma unroll
  for (int i = 0; i < 16; ++i) acc[i] = zero4();
  #pragma unroll 1
  for (int ks = 0; ks < 16; ++ks){
    bf16x8 af = __builtin_bit_cast(bf16x8,
        *(const u16x8*)&AS[(((rt*16 + ks)*4 + q)*16 + c)*8]);
    #pragma unroll
    for (int i = 0; i < 16; ++i){
      const int nt = nh * 16 + i;
      bf16x8 bf = __builtin_bit_cast(bf16x8,
          *(const u16x8*)(fB + (((size_t)ks * 32 + nt) * 64 + lane) * 8));
      acc[i] = MFMA16x16(af, bf, acc[i]);
    }
  }
  __syncthreads();                          // all stage-2 reads done
  #pragma unroll
  for (int i = 0; i < 16; ++i){
    const int cl = (nh * 16 + i) * 16 + c;
    const int ks2 = cl >> 5, qq = (cl >> 3) & 3, j = cl & 7;
    #pragma unroll
    for (int r = 0; r < 4; ++r){
      const int m = q*4 + r;
      float v = acc[i][r];
      v = fmaxf(v, 0.1f * v);
      AS[(((rt*16 + ks2)*4 + qq)*16 + m)*8 + j] =
          (cl < 500) ? f2bf(v) : ((cl == 511) ? (u16)0x3F80 : (u16)0);
    }
  }
  __syncthreads();

  // ---- stage 3 ----
  if (mode == 0){
    if (w < 4){
      const int rt3 = w;
      f32x4 a3 = zero4();
      #pragma unroll 1
      for (int ks = 0; ks < 16; ++ks){
        bf16x8 af = __builtin_bit_cast(bf16x8,
            *(const u16x8*)&AS[(((rt3*16 + ks)*4 + q)*16 + c)*8]);
        bf16x8 bf = __builtin_bit_cast(bf16x8,
            *(const u16x8*)(f3 + (((size_t)ks * 64) + lane) * 8));
        a3 = MFMA16x16(af, bf, a3);
      }
      if (c < 6){
        #pragma unroll
        for (int r = 0; r < 4; ++r)
          o0[(rowbase + rt3*16 + q*4 + r)*8 + c] = a3[r];
      }
    }
  } else {
    const int rt3 = w & 3, hh = w >> 2;
    f32x4 a3[3];
    #pragma unroll
    for (int ii = 0; ii < 3; ++ii) a3[ii] = zero4();
    #pragma unroll 1
    for (int ks = 0; ks < 16; ++ks){
      bf16x8 af = __builtin_bit_cast(bf16x8,
          *(const u16x8*)&AS[(((rt3*16 + ks)*4 + q)*16 + c)*8]);
      #pragma unroll
      for (int ii = 0; ii < 3; ++ii){
        const int nt = hh*3 + ii;
        bf16x8 bf = __builtin_bit_cast(bf16x8,
            *(const u16x8*)(f3 + (((size_t)ks * 6 + nt) * 64 + lane) * 8));
        a3[ii] = MFMA16x16(af, bf, a3[ii]);
      }
    }
    #pragma unroll
    for (int ii = 0; ii < 3; ++ii){
      const int cc = (hh*3 + ii)*16 + c;
      const int grp = cc / 48;
      const int cl = cc - grp * 48;
      if (cl < 38){
        #pragma unroll
        for (int r = 0; r < 4; ++r){
          const size_t row = rowbase + rt3*16 + q*4 + r;
          if (grp == 0) o0[row*38 + cl] = a3[ii][r];
          else          o1[row*38 + cl] = fast_softplus(a3[ii][r]) + 1e-4f;
        }
      }
    }
  }
}

// ---------------------------------------------------------------------------
// Sequential latent scan: only the 3x3 z-feedback part (h-part precomputed).
// ---------------------------------------------------------------------------
__global__ void scan_kernel(const float* __restrict__ hm, const float* __restrict__ eps,
                            const float* __restrict__ zmW, const float* __restrict__ zsW,
                            float* __restrict__ zgen, float* __restrict__ zmu,
                            float* __restrict__ zstd)
{
  int b = blockIdx.x * blockDim.x + threadIdx.x;
  if (b >= 512) return;
  float Wm[3][3], Ws[3][3];
  #pragma unroll
  for (int j = 0; j < 3; ++j)
    #pragma unroll
    for (int k = 0; k < 3; ++k){
      Wm[j][k] = zmW[j * 503 + 500 + k];
      Ws[j][k] = zsW[j * 503 + 500 + k];
    }
  float z0 = 0.f, z1 = 0.f, z2 = 0.f;
  for (int t = 0; t < 100; ++t){
    size_t row = (size_t)b * 100 + t;
    const float* h = hm + row * 8;
    const float* e = eps + row * 3;
    float zn[3];
    #pragma unroll
    for (int j = 0; j < 3; ++j){
      float m_ = h[j]     + Wm[j][0]*z0 + Wm[j][1]*z1 + Wm[j][2]*z2;
      float p_ = h[3 + j] + Ws[j][0]*z0 + Ws[j][1]*z1 + Ws[j][2]*z2;
      float s_ = fast_softplus(p_) + 1e-4f;
      float zv = m_ + s_ * e[j];
      zgen[row * 3 + j] = zv;
      zmu [row * 3 + j] = m_;
      zstd[row * 3 + j] = s_;
      zn[j] = zv;
    }
    z0 = zn[0]; z1 = zn[1]; z2 = zn[2];
  }
}

// ---------------------------------------------------------------------------
// Planar flow (parallel over 51200); also emits packed bf16 z for dec GRU.
// ---------------------------------------------------------------------------
__global__ void flow_kernel(const float* __restrict__ zgen, const float* __restrict__ fp,
                            float* __restrict__ zfin, float* __restrict__ ldj,
                            u16* __restrict__ zf16)
{
  int idx = blockIdx.x * blockDim.x + threadIdx.x;
  if (idx >= 51200) return;
  float z0 = zgen[idx*3+0], z1 = zgen[idx*3+1], z2 = zgen[idx*3+2];
  float ld = 0.f;
  #pragma unroll 1
  for (int l = 0; l < 20; ++l){
    const float* p = fp + l * 8;
    float lin = z0*p[0] + z1*p[1] + z2*p[2] + p[3];
    float tt = fast_tanh(lin);
    z0 += p[4]*tt; z1 += p[5]*tt; z2 += p[6]*tt;
    float det = 1.f + (1.f - tt*tt) * p[7];
    ld += __logf(fabsf(det) + 1e-7f);
  }
  zfin[idx*3+0] = z0; zfin[idx*3+1] = z1; zfin[idx*3+2] = z2;
  ldj[idx] = ld;
  u16x4 o; o[0] = f2bf(z0); o[1] = f2bf(z1); o[2] = f2bf(z2); o[3] = 0x3F80;
  *(u16x4*)(zf16 + (size_t)idx * 4) = o;
}

// ---------------------------------------------------------------------------
extern "C" void kernel_launch(void* const* d_in, const int* in_sizes, int n_in,
                              void* d_out, int out_size, void* d_ws, size_t ws_size,
                              hipStream_t stream)
{
  const float* x       = (const float*)d_in[0];
  const float* eps     = (const float*)d_in[1];
  const float* enc_Wih = (const float*)d_in[2];
  const float* enc_Whh = (const float*)d_in[3];
  const float* enc_bih = (const float*)d_in[4];
  const float* enc_bhh = (const float*)d_in[5];
  const float* enc_W1  = (const float*)d_in[6];
  const float* enc_b1  = (const float*)d_in[7];
  const float* enc_W2  = (const float*)d_in[8];
  const float* enc_b2  = (const float*)d_in[9];
  const float* zm_W    = (const float*)d_in[10];
  const float* zm_b    = (const float*)d_in[11];
  const float* zs_W    = (const float*)d_in[12];
  const float* zs_b    = (const float*)d_in[13];
  const float* flow_w  = (const float*)d_in[14];
  const float* flow_b  = (const float*)d_in[15];
  const float* flow_u  = (const float*)d_in[16];
  const float* dec_Wih = (const float*)d_in[17];
  const float* dec_Whh = (const float*)d_in[18];
  const float* dec_bih = (const float*)d_in[19];
  const float* dec_bhh = (const float*)d_in[20];
  const float* dec_W1  = (const float*)d_in[21];
  const float* dec_b1  = (const float*)d_in[22];
  const float* dec_W2  = (const float*)d_in[23];
  const float* dec_b2  = (const float*)d_in[24];
  const float* xm_W    = (const float*)d_in[25];
  const float* xm_b    = (const float*)d_in[26];
  const float* xs_W    = (const float*)d_in[27];
  const float* xs_b    = (const float*)d_in[28];
  (void)in_sizes; (void)n_in; (void)out_size; (void)ws_size;

  float* out    = (float*)d_out;
  float* r_mu   = out;                 // [512,100,38]
  float* r_std  = out + 1945600;       // [512,100,38]
  float* r_zgen = out + 3891200;       // [512,100,3]
  float* r_zfin = out + 4044800;       // [512,100,3]
  float* r_zmu  = out + 4198400;       // [512,100,3]
  float* r_zstd = out + 4352000;       // [512,100,3]
  float* r_ldj  = out + 4505600;       // [512,100,1]

  char* ws = (char*)d_ws;
  size_t off = 0;
  auto alloc = [&](size_t bytes)->char*{
    char* p = ws + off;
    off += (bytes + 255) & ~(size_t)255;
    return p;
  };
  u16* H1    = (u16*)alloc((size_t)51200*512*2);     // GRU hidden states
  u16* BIG   = (u16*)alloc((size_t)51200*1536*2);    // enc gi buffer
  u16* ENCF  = (u16*)alloc((size_t)16*96*512*2);
  u16* DECF  = (u16*)alloc((size_t)16*96*512*2);
  u16* EGIF  = (u16*)alloc((size_t)2*96*512*2);
  u16* PF0   = (u16*)alloc((size_t)16*32*512*2);
  u16* PF1   = (u16*)alloc((size_t)16*32*512*2);
  u16* PF2   = (u16*)alloc((size_t)16*32*512*2);
  u16* PF3   = (u16*)alloc((size_t)16*32*512*2);
  u16* ZFR   = (u16*)alloc((size_t)16*1*512*2);
  u16* HFR   = (u16*)alloc((size_t)16*6*512*2);
  float* FPP = (float*)alloc((size_t)20*8*4);
  float* HM  = (float*)alloc((size_t)51200*8*4);
  u16* ZF16  = (u16*)alloc((size_t)51200*4*2);
  u32* HBUF  = (u32*)alloc((size_t)32*2*16*512*2);   // h exchange (packed bf16 pairs)
  u32* FLG   = (u32*)alloc((size_t)2*32*128*4);      // 512 B/group flag arrays

  hipMemsetAsync(FLG, 0, 2*32*128*4, stream);
  build_all<<<10849,256,0,stream>>>(ENCF,DECF,EGIF,PF0,PF1,PF2,PF3,ZFR,HFR,FPP,
      enc_Whh,enc_bhh,enc_Wih,dec_Whh,dec_bhh,
      enc_W1,enc_b1,enc_W2,enc_b2,dec_W1,dec_b1,dec_W2,dec_b2,
      zm_W,zm_b,zs_W,zs_b,xm_W,xm_b,xs_W,xs_b,flow_w,flow_b,flow_u);

  // --- encoder ---
  gi_enc_kernel<<<1600,512,0,stream>>>(x, EGIF, enc_bih, BIG);
  gru4_kernel<<<256,512,0,stream>>>(ENCF, BIG, nullptr, nullptr, nullptr,
                                    HBUF, H1, FLG);
  post_chain<<<800,512,0,stream>>>(H1, PF0, PF1, ZFR, HM, nullptr, 0);

  // --- latent scan + planar flow ---
  scan_kernel<<<2,256,0,stream>>>(HM, eps, zm_W, zs_W, r_zgen, r_zmu, r_zstd);
  flow_kernel<<<200,256,0,stream>>>(r_zgen, FPP, r_zfin, r_ldj, ZF16);

  // --- decoder ---
  gru4_kernel<<<256,512,0,stream>>>(DECF, nullptr, (const u64*)ZF16,
                                    dec_Wih, dec_bih, HBUF, H1, FLG + 32*128);
  post_chain<<<800,512,0,stream>>>(H1, PF2, PF3, HFR, r_mu, r_std, 1);
}

// Round 7
// 1762.658 us; speedup vs baseline: 1.3052x; 1.0912x over previous
//
#include <hip/hip_runtime.h>

typedef unsigned short u16;
typedef unsigned int u32;
typedef unsigned long long u64;
typedef __bf16 bf16x8 __attribute__((ext_vector_type(8)));
typedef float f32x4 __attribute__((ext_vector_type(4)));
typedef u16 u16x8 __attribute__((ext_vector_type(8)));
typedef u16 u16x4 __attribute__((ext_vector_type(4)));

struct u64pair { u64 a, b; };

#define MFMA16x16(a,b,c) __builtin_amdgcn_mfma_f32_16x16x32_bf16((a),(b),(c),0,0,0)

static __device__ __forceinline__ u16 f2bf(float f){
  u32 u = __builtin_bit_cast(u32, f);
  u += 0x7fffu + ((u >> 16) & 1u);
  return (u16)(u >> 16);
}
static __device__ __forceinline__ float bf2f(u16 h){
  u32 u = ((u32)h) << 16;
  return __builtin_bit_cast(float, u);
}
static __device__ __forceinline__ float fast_sigmoid(float x){
  return 1.f / (1.f + __expf(-x));
}
static __device__ __forceinline__ float fast_tanh(float x){
  float e = __expf(2.f * x);
  return 1.f - 2.f / (e + 1.f);
}
static __device__ __forceinline__ float fast_softplus(float x){
  return (x > 15.f) ? x : __logf(1.f + __expf(x));
}
static __device__ __forceinline__ f32x4 zero4(){
  f32x4 v; v[0]=0.f; v[1]=0.f; v[2]=0.f; v[3]=0.f; return v;
}

// ---------------------------------------------------------------------------
// Weight swizzle into MFMA B-fragment order:
// dst[ks][nt][lane][j] = W[k = ks*32 + (lane>>4)*8 + j][ncol = nt*16 + (lane&15)]
// modes: 0 GRU hidden  2 post(500x500+b)  3 zW  4 heads  5 enc Wih
// ---------------------------------------------------------------------------
static __device__ __forceinline__ void build_one(
    u16* __restrict__ dst, int mode, int NT, int idx,
    const float* __restrict__ W0, const float* __restrict__ b0,
    const float* __restrict__ W1, const float* __restrict__ b1)
{
  int j    = idx & 7;
  int lane = (idx >> 3) & 63;
  int ntks = idx >> 9;
  int nt   = ntks % NT;
  int ks   = ntks / NT;
  int k    = ks * 32 + ((lane >> 4) << 3) + j;
  int ncol = (nt << 4) + (lane & 15);
  float v = 0.f;
  if (mode == 0){                         // GRU hidden: rows 0..499 Whh^T, 511 bhh
    int g = ncol >> 9;
    int jin = ncol & 511;
    if (jin < 500){
      int row = g * 500 + jin;
      if (k < 500) v = W0[row * 500 + k];
      else if (k == 511) v = b0[row];
    }
  } else if (mode == 2){                  // post: W0 [500][500], bias row 511
    if (ncol < 500){
      if (k < 500) v = W0[ncol * 500 + k];
      else if (k == 511) v = b0[ncol];
    }
  } else if (mode == 3){                  // zW: cols 0..2 zm (W0 [3][503]), 3..5 zs
    int c = ncol;
    if (c < 3){
      if (k < 500) v = W0[c * 503 + k];
      else if (k == 511) v = b0[c];
    } else if (c < 6){
      int cc = c - 3;
      if (k < 500) v = W1[cc * 503 + k];
      else if (k == 511) v = b1[cc];
    }
  } else if (mode == 4){                  // heads: cols 0..47 xm (<38), 48..95 xs
    int grp = ncol / 48;
    int cc  = ncol - grp * 48;
    if (grp < 2 && cc < 38){
      const float* W  = grp ? W1 : W0;
      const float* bb = grp ? b1 : b0;
      if (k < 500) v = W[cc * 500 + k];
      else if (k == 511) v = bb[cc];
    }
  } else {                                // mode 5: enc Wih [1500][38]
    int g = ncol >> 9;
    int jin = ncol & 511;
    if (jin < 500 && k < 38) v = W0[(g * 500 + jin) * 38 + k];
  }
  dst[idx] = f2bf(v);
}

// One launch for all weight prep + flow params + counter zeroing.
__global__ void build_all(
    u16* ENCF, u16* DECF, u16* EGIF, u16* PF0, u16* PF1, u16* PF2, u16* PF3,
    u16* ZFR, u16* HFR, float* FPP, u32* CNT,
    const float* enc_Whh, const float* enc_bhh, const float* enc_Wih,
    const float* dec_Whh, const float* dec_bhh,
    const float* enc_W1, const float* enc_b1, const float* enc_W2, const float* enc_b2,
    const float* dec_W1, const float* dec_b1, const float* dec_W2, const float* dec_b2,
    const float* zm_W, const float* zm_b, const float* zs_W, const float* zs_b,
    const float* xm_W, const float* xm_b, const float* xs_W, const float* xs_b,
    const float* flow_w, const float* flow_b, const float* flow_u)
{
  const int b = blockIdx.x, tid = threadIdx.x;
  if      (b < 3072)  build_one(ENCF,0,96,(b       )*256+tid, enc_Whh,enc_bhh,0,0);
  else if (b < 6144)  build_one(DECF,0,96,(b- 3072 )*256+tid, dec_Whh,dec_bhh,0,0);
  else if (b < 6528)  build_one(EGIF,5,96,(b- 6144 )*256+tid, enc_Wih,0,0,0);
  else if (b < 7552)  build_one(PF0 ,2,32,(b- 6528 )*256+tid, enc_W1,enc_b1,0,0);
  else if (b < 8576)  build_one(PF1 ,2,32,(b- 7552 )*256+tid, enc_W2,enc_b2,0,0);
  else if (b < 9600)  build_one(PF2 ,2,32,(b- 8576 )*256+tid, dec_W1,dec_b1,0,0);
  else if (b < 10624) build_one(PF3 ,2,32,(b- 9600 )*256+tid, dec_W2,dec_b2,0,0);
  else if (b < 10656) build_one(ZFR ,3, 1,(b-10624 )*256+tid, zm_W,zm_b,zs_W,zs_b);
  else if (b < 10848) build_one(HFR ,4, 6,(b-10656 )*256+tid, xm_W,xm_b,xs_W,xs_b);
  else if (b == 10848){
    if (tid < 20){
      int l = tid;
      float w0 = flow_w[l*3+0], w1 = flow_w[l*3+1], w2 = flow_w[l*3+2];
      float u0 = flow_u[l*3+0], u1 = flow_u[l*3+1], u2 = flow_u[l*3+2];
      float wu = w0*u0 + w1*u1 + w2*u2;
      float m  = -1.f + fast_softplus(wu);
      float ww = w0*w0 + w1*w1 + w2*w2 + 1e-7f;
      float sc = (m - wu) / ww;
      float uh0 = u0 + sc*w0, uh1 = u1 + sc*w1, uh2 = u2 + sc*w2;
      float uw  = uh0*w0 + uh1*w1 + uh2*w2;
      FPP[l*8+0]=w0; FPP[l*8+1]=w1; FPP[l*8+2]=w2; FPP[l*8+3]=flow_b[l];
      FPP[l*8+4]=uh0; FPP[l*8+5]=uh1; FPP[l*8+6]=uh2; FPP[l*8+7]=uw;
    }
  } else {
    for (int i = tid; i < 8192; i += 256) CNT[i] = 0;   // enc+dec counter arrays
  }
}

// ---------------------------------------------------------------------------
// Encoder input-gates precompute: gi[51200][1536] = x[51200][38] @ Wih^T + bih
// ---------------------------------------------------------------------------
__global__ __launch_bounds__(512, 2) void gi_enc_kernel(
    const float* __restrict__ x, const u16* __restrict__ frag2,
    const float* __restrict__ bih, u16* __restrict__ gi)
{
  const int tid = threadIdx.x, lane = tid & 63, v = tid >> 6;
  const int q = lane >> 4, c = lane & 15;
  const size_t rowbase = (size_t)blockIdx.x * 32;
  u16 a[2][2][8];
  #pragma unroll
  for (int tile = 0; tile < 2; ++tile){
    const float* xr = x + (rowbase + tile*16 + c) * 38;
    #pragma unroll
    for (int j = 0; j < 8; ++j){
      int k0 = q*8 + j;
      a[tile][0][j] = f2bf(xr[k0]);
      int k1 = 32 + q*8 + j;
      a[tile][1][j] = (k1 < 38) ? f2bf(xr[k1]) : (u16)0;
    }
  }
  f32x4 acc[2][12];
  #pragma unroll
  for (int tile = 0; tile < 2; ++tile)
    #pragma unroll
    for (int i = 0; i < 12; ++i) acc[tile][i] = zero4();
  #pragma unroll
  for (int i = 0; i < 12; ++i){
    const int nt = v*12 + i;
    bf16x8 b0 = __builtin_bit_cast(bf16x8,
        *(const u16x8*)(frag2 + (((size_t)0*96 + nt)*64 + lane)*8));
    bf16x8 b1 = __builtin_bit_cast(bf16x8,
        *(const u16x8*)(frag2 + (((size_t)1*96 + nt)*64 + lane)*8));
    #pragma unroll
    for (int tile = 0; tile < 2; ++tile){
      bf16x8 a0 = __builtin_bit_cast(bf16x8, *(const u16x8*)a[tile][0]);
      bf16x8 a1 = __builtin_bit_cast(bf16x8, *(const u16x8*)a[tile][1]);
      acc[tile][i] = MFMA16x16(a0, b0, acc[tile][i]);
      acc[tile][i] = MFMA16x16(a1, b1, acc[tile][i]);
    }
  }
  #pragma unroll
  for (int i = 0; i < 12; ++i){
    const int nt = v*12 + i;
    const int ncol = nt*16 + c;
    const int g = ncol >> 9, jin = ncol & 511;
    const float bias = (jin < 500) ? bih[g*500 + jin] : 0.f;
    #pragma unroll
    for (int tile = 0; tile < 2; ++tile)
      #pragma unroll
      for (int r = 0; r < 4; ++r){
        size_t row = rowbase + tile*16 + q*4 + r;
        gi[row*1536 + ncol] = f2bf(acc[tile][i][r] + bias);
      }
  }
}

// ---------------------------------------------------------------------------
// Register-resident cooperative GRU — R3's proven sync scheme (543 us):
// per-group counter, tid0 polls 8*(t+1), relaxed sc1 (IF) exchange, 3
// barriers/step, __syncthreads drains vmcnt before the signal add.
// Grid 256 = 32 batch-groups x 8 col-slices; 8 waves = 4 nt x 2 K-halves.
// enc: gi streamed from gix. dec: gi computed on the fly from rank-3 z
// (proven in R4/R5; kills the 109 MB dec gi stream).
// 84 KB LDS forces 1 block/CU -> 256 blocks co-resident.
// ---------------------------------------------------------------------------
__global__ __launch_bounds__(512, 2) void gru6_kernel(
    const u16* __restrict__ frag, const u16* __restrict__ gix,
    const u64* __restrict__ zsrc, const float* __restrict__ Wih3,
    const float* __restrict__ bih3,
    u32* __restrict__ hbufbase, u16* __restrict__ hout, u32* __restrict__ cntbase)
{
  __shared__ f32x4 red[5376];               // 86016 B: forces 1 block/CU
  const int tid  = threadIdx.x, lane = tid & 63;
  const int wv   = tid >> 6, igrp = wv & 3, half = wv >> 2;
  const int q    = lane >> 4, c = lane & 15;
  const int gid  = blockIdx.x & 31, s = blockIdx.x >> 5;
  const int b0   = gid * 16;
  const int col  = (s*4 + igrp)*16 + c;
  u32* cnt = cntbase + gid * 128;           // 512 B stride: no flag-line sharing
  u32* hb  = hbufbase + (size_t)gid * 8192; // 2 bufs x 16x256 u32 (=16x512 bf16)

  // --- weights into VGPRs (held for all steps) ---
  u16x8 wf[3][8];
  #pragma unroll
  for (int kk = 0; kk < 8; ++kk){
    const int ks = half*8 + kk;
    #pragma unroll
    for (int g = 0; g < 3; ++g){
      const int nt = g*32 + s*4 + igrp;
      wf[g][kk] = *(const u16x8*)(frag + (((size_t)ks*96 + nt)*64 + lane)*8);
    }
  }
  // --- decoder-mode per-lane gi weights (z is rank 3) ---
  float wz[3][3] = {{0,0,0},{0,0,0},{0,0,0}}, wb[3] = {0,0,0};
  if (!gix && col < 500){
    #pragma unroll
    for (int g = 0; g < 3; ++g){
      #pragma unroll
      for (int k = 0; k < 3; ++k) wz[g][k] = Wih3[(g*500 + col)*3 + k];
      wb[g] = bih3[g*500 + col];
    }
  }

  float hold[4] = {0.f, 0.f, 0.f, 0.f};
  u16 giv[3][4];
  u64 zv[4];
  if (half == 0){
    // h0 = 0 (+ col511 = 1.0), packed u32 pairs via IF (sc1)
    u32 me = (col == 511) ? 0x3F80u : 0u;
    u32 pr = __shfl_xor(me, 1, 64);
    if (!(c & 1)){
      u32 val = me | (pr << 16);
      #pragma unroll
      for (int r = 0; r < 4; ++r)
        __hip_atomic_store(hb + (q*4+r)*256 + (col>>1), val,
                           __ATOMIC_RELAXED, __HIP_MEMORY_SCOPE_AGENT);
    }
    // prefetch inputs for t=0
    if (gix){
      #pragma unroll
      for (int g = 0; g < 3; ++g)
        #pragma unroll
        for (int r = 0; r < 4; ++r)
          giv[g][r] = __builtin_nontemporal_load(
              gix + ((size_t)(b0 + q*4 + r)*100 + 0)*1536 + g*512 + col);
    } else {
      #pragma unroll
      for (int r = 0; r < 4; ++r)
        zv[r] = zsrc[(size_t)(b0 + q*4 + r)*100 + 0];
    }
  }
  __syncthreads();                          // drains vmcnt(0): h0 stores acked at IF
  if (tid == 0)
    __hip_atomic_fetch_add(cnt, 1u, __ATOMIC_RELAXED, __HIP_MEMORY_SCOPE_AGENT);

  #pragma unroll 1
  for (int t = 0; t < 100; ++t){
    if (tid == 0){
      const u32 target = 8u*(u32)(t+1);
      long guard = 0;
      while (__hip_atomic_load(cnt, __ATOMIC_RELAXED, __HIP_MEMORY_SCOPE_AGENT) < target){
        __builtin_amdgcn_s_sleep(1);
        if (++guard > (1L<<27)) break;      // hang-breaker
      }
    }
    __syncthreads();                        // barrier 1: h_t visible
    const u64* cur64 = (const u64*)(hb + (t & 1)*4096);
    u32*       nxt   = hb + ((t+1) & 1)*4096;

    f32x4 acc0 = zero4(), acc1 = zero4(), acc2 = zero4();
    #pragma unroll
    for (int kk = 0; kk < 8; ++kk){
      const int ks = half*8 + kk;
      const u64* p = cur64 + c*128 + ks*8 + q*2;
      u64pair pp;
      pp.a = __hip_atomic_load(p,     __ATOMIC_RELAXED, __HIP_MEMORY_SCOPE_AGENT);
      pp.b = __hip_atomic_load(p + 1, __ATOMIC_RELAXED, __HIP_MEMORY_SCOPE_AGENT);
      bf16x8 af = __builtin_bit_cast(bf16x8, pp);
      acc0 = MFMA16x16(af, __builtin_bit_cast(bf16x8, wf[0][kk]), acc0);
      acc1 = MFMA16x16(af, __builtin_bit_cast(bf16x8, wf[1][kk]), acc1);
      acc2 = MFMA16x16(af, __builtin_bit_cast(bf16x8, wf[2][kk]), acc2);
    }
    if (half == 1){
      red[(igrp*3 + 0)*64 + lane] = acc0;
      red[(igrp*3 + 1)*64 + lane] = acc1;
      red[(igrp*3 + 2)*64 + lane] = acc2;
    }
    __syncthreads();                        // barrier 2: partials in LDS
    u16 hvv[4];
    if (half == 0){
      const f32x4 p0 = red[(igrp*3+0)*64 + lane];
      const f32x4 p1 = red[(igrp*3+1)*64 + lane];
      const f32x4 p2 = red[(igrp*3+2)*64 + lane];
      #pragma unroll
      for (int r = 0; r < 4; ++r){
        float gr, gz, gn;
        if (gix){
          gr = bf2f(giv[0][r]); gz = bf2f(giv[1][r]); gn = bf2f(giv[2][r]);
        } else {
          float z0 = bf2f((u16)(zv[r]));
          float z1 = bf2f((u16)(zv[r] >> 16));
          float z2 = bf2f((u16)(zv[r] >> 32));
          gr = z0*wz[0][0] + z1*wz[0][1] + z2*wz[0][2] + wb[0];
          gz = z0*wz[1][0] + z1*wz[1][1] + z2*wz[1][2] + wb[1];
          gn = z0*wz[2][0] + z1*wz[2][1] + z2*wz[2][2] + wb[2];
        }
        float ar = acc0[r] + p0[r] + gr;
        float az = acc1[r] + p1[r] + gz;
        float an = acc2[r] + p2[r];
        float rr = fast_sigmoid(ar);
        float zz = fast_sigmoid(az);
        float nn = fast_tanh(gn + rr*an);
        float h  = (1.f - zz)*nn + zz*hold[r];
        hold[r] = h;
        u16 hv16 = (col < 500) ? f2bf(h) : ((col == 511) ? (u16)0x3F80 : (u16)0);
        hvv[r] = hv16;
        u32 me = hv16;
        u32 pr = __shfl_xor(me, 1, 64);
        if (!(c & 1))
          __hip_atomic_store(nxt + (q*4+r)*256 + (col>>1), me | (pr << 16),
                             __ATOMIC_RELAXED, __HIP_MEMORY_SCOPE_AGENT);
      }
    }
    __syncthreads();                        // barrier 3: drains vmcnt -> IF visible
    if (tid == 0)
      __hip_atomic_fetch_add(cnt, 1u, __ATOMIC_RELAXED, __HIP_MEMORY_SCOPE_AGENT);
    if (half == 0){
      #pragma unroll
      for (int r = 0; r < 4; ++r)
        __builtin_nontemporal_store(hvv[r],
            hout + ((size_t)(b0 + q*4 + r)*100 + t)*512 + col);
      if (t < 99){
        if (gix){
          #pragma unroll
          for (int g = 0; g < 3; ++g)
            #pragma unroll
            for (int r = 0; r < 4; ++r)
              giv[g][r] = __builtin_nontemporal_load(
                  gix + ((size_t)(b0 + q*4 + r)*100 + (t+1))*1536 + g*512 + col);
        } else {
          #pragma unroll
          for (int r = 0; r < 4; ++r)
            zv[r] = zsrc[(size_t)(b0 + q*4 + r)*100 + (t+1)];
        }
      }
    }
  }
}

// ---------------------------------------------------------------------------
// Fused post-net chain: P1 = lrelu(A@fA), P2 = lrelu(P1@fB), then
// mode 0: hm[51200][8] = P2 @ ZFR   mode 1: heads (mu, softplus std).
// ---------------------------------------------------------------------------
__global__ __launch_bounds__(512, 4) void post_chain(
    const u16* __restrict__ A, const u16* __restrict__ fA,
    const u16* __restrict__ fB, const u16* __restrict__ f3,
    float* __restrict__ o0, float* __restrict__ o1, int mode)
{
  __shared__ u16 AS[32768];                 // [rt4][ks16][qq4][m16][j8]
  const int tid = threadIdx.x, lane = tid & 63, w = tid >> 6;
  const int q = lane >> 4, c = lane & 15;
  const int rt = w & 3, nh = w >> 2;
  const size_t rowbase = (size_t)blockIdx.x * 64;

  // ---- stage 1 ----
  f32x4 acc[16];
  #pragma unroll
  for (int i = 0; i < 16; ++i) acc[i] = zero4();
  {
    const u16* Ar = A + (rowbase + rt*16 + c) * 512 + q * 8;
    #pragma unroll 1
    for (int ks = 0; ks < 16; ++ks){
      bf16x8 af = __builtin_bit_cast(bf16x8, *(const u16x8*)(Ar + ks * 32));
      #pragma unroll
      for (int i = 0; i < 16; ++i){
        const int nt = nh * 16 + i;
        bf16x8 bf = __builtin_bit_cast(bf16x8,
            *(const u16x8*)(fA + (((size_t)ks * 32 + nt) * 64 + lane) * 8));
        acc[i] = MFMA16x16(af, bf, acc[i]);
      }
    }
  }
  #pragma unroll
  for (int i = 0; i < 16; ++i){
    const int cl = (nh * 16 + i) * 16 + c;
    const int ks2 = cl >> 5, qq = (cl >> 3) & 3, j = cl & 7;
    #pragma unroll
    for (int r = 0; r < 4; ++r){
      const int m = q*4 + r;
      float v = acc[i][r];
      v = fmaxf(v, 0.1f * v);
      AS[(((rt*16 + ks2)*4 + qq)*16 + m)*8 + j] =
          (cl < 500) ? f2bf(v) : ((cl == 511) ? (u16)0x3F80 : (u16)0);
    }
  }
  __syncthreads();

  // ---- stage 2 ----
  #pragma unroll
  for (int i = 0; i < 16; ++i) acc[i] = zero4();
  #pragma unroll 1
  for (int ks = 0; ks < 16; ++ks){
    bf16x8 af = __builtin_bit_cast(bf16x8,
        *(const u16x8*)&AS[(((rt*16 + ks)*4 + q)*16 + c)*8]);
    #pragma unroll
    for (int i = 0; i < 16; ++i){
      const int nt = nh * 16 + i;
      bf16x8 bf = __builtin_bit_cast(bf16x8,
          *(const u16x8*)(fB + (((size_t)ks * 32 + nt) * 64 + lane) * 8));
      acc[i] = MFMA16x16(af, bf, acc[i]);
    }
  }
  __syncthreads();
  #pragma unroll
  for (int i = 0; i < 16; ++i){
    const int cl = (nh * 16 + i) * 16 + c;
    const int ks2 = cl >> 5, qq = (cl >> 3) & 3, j = cl & 7;
    #pragma unroll
    for (int r = 0; r < 4; ++r){
      const int m = q*4 + r;
      float v = acc[i][r];
      v = fmaxf(v, 0.1f * v);
      AS[(((rt*16 + ks2)*4 + qq)*16 + m)*8 + j] =
          (cl < 500) ? f2bf(v) : ((cl == 511) ? (u16)0x3F80 : (u16)0);
    }
  }
  __syncthreads();

  // ---- stage 3 ----
  if (mode == 0){
    if (w < 4){
      const int rt3 = w;
      f32x4 a3 = zero4();
      #pragma unroll 1
      for (int ks = 0; ks < 16; ++ks){
        bf16x8 af = __builtin_bit_cast(bf16x8,
            *(const u16x8*)&AS[(((rt3*16 + ks)*4 + q)*16 + c)*8]);
        bf16x8 bf = __builtin_bit_cast(bf16x8,
            *(const u16x8*)(f3 + (((size_t)ks * 64) + lane) * 8));
        a3 = MFMA16x16(af, bf, a3);
      }
      if (c < 6){
        #pragma unroll
        for (int r = 0; r < 4; ++r)
          o0[(rowbase + rt3*16 + q*4 + r)*8 + c] = a3[r];
      }
    }
  } else {
    const int rt3 = w & 3, hh = w >> 2;
    f32x4 a3[3];
    #pragma unroll
    for (int ii = 0; ii < 3; ++ii) a3[ii] = zero4();
    #pragma unroll 1
    for (int ks = 0; ks < 16; ++ks){
      bf16x8 af = __builtin_bit_cast(bf16x8,
          *(const u16x8*)&AS[(((rt3*16 + ks)*4 + q)*16 + c)*8]);
      #pragma unroll
      for (int ii = 0; ii < 3; ++ii){
        const int nt = hh*3 + ii;
        bf16x8 bf = __builtin_bit_cast(bf16x8,
            *(const u16x8*)(f3 + (((size_t)ks * 6 + nt) * 64 + lane) * 8));
        a3[ii] = MFMA16x16(af, bf, a3[ii]);
      }
    }
    #pragma unroll
    for (int ii = 0; ii < 3; ++ii){
      const int cc = (hh*3 + ii)*16 + c;
      const int grp = cc / 48;
      const int cl = cc - grp * 48;
      if (cl < 38){
        #pragma unroll
        for (int r = 0; r < 4; ++r){
          const size_t row = rowbase + rt3*16 + q*4 + r;
          if (grp == 0) o0[row*38 + cl] = a3[ii][r];
          else          o1[row*38 + cl] = fast_softplus(a3[ii][r]) + 1e-4f;
        }
      }
    }
  }
}

// ---------------------------------------------------------------------------
// Sequential latent scan: only the 3x3 z-feedback part (h-part precomputed).
// ---------------------------------------------------------------------------
__global__ void scan_kernel(const float* __restrict__ hm, const float* __restrict__ eps,
                            const float* __restrict__ zmW, const float* __restrict__ zsW,
                            float* __restrict__ zgen, float* __restrict__ zmu,
                            float* __restrict__ zstd)
{
  int b = blockIdx.x * blockDim.x + threadIdx.x;
  if (b >= 512) return;
  float Wm[3][3], Ws[3][3];
  #pragma unroll
  for (int j = 0; j < 3; ++j)
    #pragma unroll
    for (int k = 0; k < 3; ++k){
      Wm[j][k] = zmW[j * 503 + 500 + k];
      Ws[j][k] = zsW[j * 503 + 500 + k];
    }
  float z0 = 0.f, z1 = 0.f, z2 = 0.f;
  for (int t = 0; t < 100; ++t){
    size_t row = (size_t)b * 100 + t;
    const float* h = hm + row * 8;
    const float* e = eps + row * 3;
    float zn[3];
    #pragma unroll
    for (int j = 0; j < 3; ++j){
      float m_ = h[j]     + Wm[j][0]*z0 + Wm[j][1]*z1 + Wm[j][2]*z2;
      float p_ = h[3 + j] + Ws[j][0]*z0 + Ws[j][1]*z1 + Ws[j][2]*z2;
      float s_ = fast_softplus(p_) + 1e-4f;
      float zv = m_ + s_ * e[j];
      zgen[row * 3 + j] = zv;
      zmu [row * 3 + j] = m_;
      zstd[row * 3 + j] = s_;
      zn[j] = zv;
    }
    z0 = zn[0]; z1 = zn[1]; z2 = zn[2];
  }
}

// ---------------------------------------------------------------------------
// Planar flow (parallel over 51200); also emits packed bf16 z for dec GRU.
// ---------------------------------------------------------------------------
__global__ void flow_kernel(const float* __restrict__ zgen, const float* __restrict__ fp,
                            float* __restrict__ zfin, float* __restrict__ ldj,
                            u16* __restrict__ zf16)
{
  int idx = blockIdx.x * blockDim.x + threadIdx.x;
  if (idx >= 51200) return;
  float z0 = zgen[idx*3+0], z1 = zgen[idx*3+1], z2 = zgen[idx*3+2];
  float ld = 0.f;
  #pragma unroll 1
  for (int l = 0; l < 20; ++l){
    const float* p = fp + l * 8;
    float lin = z0*p[0] + z1*p[1] + z2*p[2] + p[3];
    float tt = fast_tanh(lin);
    z0 += p[4]*tt; z1 += p[5]*tt; z2 += p[6]*tt;
    float det = 1.f + (1.f - tt*tt) * p[7];
    ld += __logf(fabsf(det) + 1e-7f);
  }
  zfin[idx*3+0] = z0; zfin[idx*3+1] = z1; zfin[idx*3+2] = z2;
  ldj[idx] = ld;
  u16x4 o; o[0] = f2bf(z0); o[1] = f2bf(z1); o[2] = f2bf(z2); o[3] = 0x3F80;
  *(u16x4*)(zf16 + (size_t)idx * 4) = o;
}

// ---------------------------------------------------------------------------
extern "C" void kernel_launch(void* const* d_in, const int* in_sizes, int n_in,
                              void* d_out, int out_size, void* d_ws, size_t ws_size,
                              hipStream_t stream)
{
  const float* x       = (const float*)d_in[0];
  const float* eps     = (const float*)d_in[1];
  const float* enc_Wih = (const float*)d_in[2];
  const float* enc_Whh = (const float*)d_in[3];
  const float* enc_bih = (const float*)d_in[4];
  const float* enc_bhh = (const float*)d_in[5];
  const float* enc_W1  = (const float*)d_in[6];
  const float* enc_b1  = (const float*)d_in[7];
  const float* enc_W2  = (const float*)d_in[8];
  const float* enc_b2  = (const float*)d_in[9];
  const float* zm_W    = (const float*)d_in[10];
  const float* zm_b    = (const float*)d_in[11];
  const float* zs_W    = (const float*)d_in[12];
  const float* zs_b    = (const float*)d_in[13];
  const float* flow_w  = (const float*)d_in[14];
  const float* flow_b  = (const float*)d_in[15];
  const float* flow_u  = (const float*)d_in[16];
  const float* dec_Wih = (const float*)d_in[17];
  const float* dec_Whh = (const float*)d_in[18];
  const float* dec_bih = (const float*)d_in[19];
  const float* dec_bhh = (const float*)d_in[20];
  const float* dec_W1  = (const float*)d_in[21];
  const float* dec_b1  = (const float*)d_in[22];
  const float* dec_W2  = (const float*)d_in[23];
  const float* dec_b2  = (const float*)d_in[24];
  const float* xm_W    = (const float*)d_in[25];
  const float* xm_b    = (const float*)d_in[26];
  const float* xs_W    = (const float*)d_in[27];
  const float* xs_b    = (const float*)d_in[28];
  (void)in_sizes; (void)n_in; (void)out_size; (void)ws_size;

  float* out    = (float*)d_out;
  float* r_mu   = out;                 // [512,100,38]
  float* r_std  = out + 1945600;       // [512,100,38]
  float* r_zgen = out + 3891200;       // [512,100,3]
  float* r_zfin = out + 4044800;       // [512,100,3]
  float* r_zmu  = out + 4198400;       // [512,100,3]
  float* r_zstd = out + 4352000;       // [512,100,3]
  float* r_ldj  = out + 4505600;       // [512,100,1]

  char* ws = (char*)d_ws;
  size_t off = 0;
  auto alloc = [&](size_t bytes)->char*{
    char* p = ws + off;
    off += (bytes + 255) & ~(size_t)255;
    return p;
  };
  u16* H1    = (u16*)alloc((size_t)51200*512*2);     // GRU hidden states
  u16* BIG   = (u16*)alloc((size_t)51200*1536*2);    // enc gi buffer
  u16* ENCF  = (u16*)alloc((size_t)16*96*512*2);
  u16* DECF  = (u16*)alloc((size_t)16*96*512*2);
  u16* EGIF  = (u16*)alloc((size_t)2*96*512*2);
  u16* PF0   = (u16*)alloc((size_t)16*32*512*2);
  u16* PF1   = (u16*)alloc((size_t)16*32*512*2);
  u16* PF2   = (u16*)alloc((size_t)16*32*512*2);
  u16* PF3   = (u16*)alloc((size_t)16*32*512*2);
  u16* ZFR   = (u16*)alloc((size_t)16*1*512*2);
  u16* HFR   = (u16*)alloc((size_t)16*6*512*2);
  float* FPP = (float*)alloc((size_t)20*8*4);
  float* HM  = (float*)alloc((size_t)51200*8*4);
  u16* ZF16  = (u16*)alloc((size_t)51200*4*2);
  u32* HBUF  = (u32*)alloc((size_t)32*2*16*512*2);   // h exchange (packed bf16 pairs)
  u32* CNT   = (u32*)alloc((size_t)2*32*128*4);      // 512 B/group counters, enc+dec

  build_all<<<10850,256,0,stream>>>(ENCF,DECF,EGIF,PF0,PF1,PF2,PF3,ZFR,HFR,FPP,CNT,
      enc_Whh,enc_bhh,enc_Wih,dec_Whh,dec_bhh,
      enc_W1,enc_b1,enc_W2,enc_b2,dec_W1,dec_b1,dec_W2,dec_b2,
      zm_W,zm_b,zs_W,zs_b,xm_W,xm_b,xs_W,xs_b,flow_w,flow_b,flow_u);

  // --- encoder ---
  gi_enc_kernel<<<1600,512,0,stream>>>(x, EGIF, enc_bih, BIG);
  gru6_kernel<<<256,512,0,stream>>>(ENCF, BIG, nullptr, nullptr, nullptr,
                                    HBUF, H1, CNT);
  post_chain<<<800,512,0,stream>>>(H1, PF0, PF1, ZFR, HM, nullptr, 0);

  // --- latent scan + planar flow ---
  scan_kernel<<<2,256,0,stream>>>(HM, eps, zm_W, zs_W, r_zgen, r_zmu, r_zstd);
  flow_kernel<<<200,256,0,stream>>>(r_zgen, FPP, r_zfin, r_ldj, ZF16);

  // --- decoder ---
  gru6_kernel<<<256,512,0,stream>>>(DECF, nullptr, (const u64*)ZF16,
                                    dec_Wih, dec_bih, HBUF, H1, CNT + 32*128);
  post_chain<<<800,512,0,stream>>>(H1, PF2, PF3, HFR, r_mu, r_std, 1);
}

// Round 8
// 1294.853 us; speedup vs baseline: 1.7767x; 1.3613x over previous
//
#include <hip/hip_runtime.h>

typedef unsigned short u16;
typedef unsigned int u32;
typedef unsigned long long u64;
typedef __bf16 bf16x8 __attribute__((ext_vector_type(8)));
typedef float f32x4 __attribute__((ext_vector_type(4)));
typedef u16 u16x8 __attribute__((ext_vector_type(8)));
typedef u16 u16x4 __attribute__((ext_vector_type(4)));
typedef u32 u32x4 __attribute__((ext_vector_type(4)));

#define MFMA16x16(a,b,c) __builtin_amdgcn_mfma_f32_16x16x32_bf16((a),(b),(c),0,0,0)

static __device__ __forceinline__ u16 f2bf(float f){
  u32 u = __builtin_bit_cast(u32, f);
  u += 0x7fffu + ((u >> 16) & 1u);
  return (u16)(u >> 16);
}
static __device__ __forceinline__ float bf2f(u16 h){
  u32 u = ((u32)h) << 16;
  return __builtin_bit_cast(float, u);
}
static __device__ __forceinline__ float fast_sigmoid(float x){
  return 1.f / (1.f + __expf(-x));
}
static __device__ __forceinline__ float fast_tanh(float x){
  float e = __expf(2.f * x);
  return 1.f - 2.f / (e + 1.f);
}
static __device__ __forceinline__ float fast_softplus(float x){
  return (x > 15.f) ? x : __logf(1.f + __expf(x));
}
static __device__ __forceinline__ f32x4 zero4(){
  f32x4 v; v[0]=0.f; v[1]=0.f; v[2]=0.f; v[3]=0.f; return v;
}

// ---------------------------------------------------------------------------
// Weight swizzle into MFMA B-fragment order:
// dst[ks][nt][lane][j] = W[k = ks*32 + (lane>>4)*8 + j][ncol = nt*16 + (lane&15)]
// modes: 0 GRU hidden  2 post(500x500+b)  3 zW  4 heads  5 enc Wih
// ---------------------------------------------------------------------------
static __device__ __forceinline__ void build_one(
    u16* __restrict__ dst, int mode, int NT, int idx,
    const float* __restrict__ W0, const float* __restrict__ b0,
    const float* __restrict__ W1, const float* __restrict__ b1)
{
  int j    = idx & 7;
  int lane = (idx >> 3) & 63;
  int ntks = idx >> 9;
  int nt   = ntks % NT;
  int ks   = ntks / NT;
  int k    = ks * 32 + ((lane >> 4) << 3) + j;
  int ncol = (nt << 4) + (lane & 15);
  float v = 0.f;
  if (mode == 0){                         // GRU hidden: rows 0..499 Whh^T, 511 bhh
    int g = ncol >> 9;
    int jin = ncol & 511;
    if (jin < 500){
      int row = g * 500 + jin;
      if (k < 500) v = W0[row * 500 + k];
      else if (k == 511) v = b0[row];
    }
  } else if (mode == 2){                  // post: W0 [500][500], bias row 511
    if (ncol < 500){
      if (k < 500) v = W0[ncol * 500 + k];
      else if (k == 511) v = b0[ncol];
    }
  } else if (mode == 3){                  // zW: cols 0..2 zm (W0 [3][503]), 3..5 zs
    int c = ncol;
    if (c < 3){
      if (k < 500) v = W0[c * 503 + k];
      else if (k == 511) v = b0[c];
    } else if (c < 6){
      int cc = c - 3;
      if (k < 500) v = W1[cc * 503 + k];
      else if (k == 511) v = b1[cc];
    }
  } else if (mode == 4){                  // heads: cols 0..47 xm (<38), 48..95 xs
    int grp = ncol / 48;
    int cc  = ncol - grp * 48;
    if (grp < 2 && cc < 38){
      const float* W  = grp ? W1 : W0;
      const float* bb = grp ? b1 : b0;
      if (k < 500) v = W[cc * 500 + k];
      else if (k == 511) v = bb[cc];
    }
  } else {                                // mode 5: enc Wih [1500][38]
    int g = ncol >> 9;
    int jin = ncol & 511;
    if (jin < 500 && k < 38) v = W0[(g * 500 + jin) * 38 + k];
  }
  dst[idx] = f2bf(v);
}

// One launch for all weight prep + flow params + counter zeroing.
__global__ void build_all(
    u16* ENCF, u16* DECF, u16* EGIF, u16* PF0, u16* PF1, u16* PF2, u16* PF3,
    u16* ZFR, u16* HFR, float* FPP, u32* CNT,
    const float* enc_Whh, const float* enc_bhh, const float* enc_Wih,
    const float* dec_Whh, const float* dec_bhh,
    const float* enc_W1, const float* enc_b1, const float* enc_W2, const float* enc_b2,
    const float* dec_W1, const float* dec_b1, const float* dec_W2, const float* dec_b2,
    const float* zm_W, const float* zm_b, const float* zs_W, const float* zs_b,
    const float* xm_W, const float* xm_b, const float* xs_W, const float* xs_b,
    const float* flow_w, const float* flow_b, const float* flow_u)
{
  const int b = blockIdx.x, tid = threadIdx.x;
  if      (b < 3072)  build_one(ENCF,0,96,(b       )*256+tid, enc_Whh,enc_bhh,0,0);
  else if (b < 6144)  build_one(DECF,0,96,(b- 3072 )*256+tid, dec_Whh,dec_bhh,0,0);
  else if (b < 6528)  build_one(EGIF,5,96,(b- 6144 )*256+tid, enc_Wih,0,0,0);
  else if (b < 7552)  build_one(PF0 ,2,32,(b- 6528 )*256+tid, enc_W1,enc_b1,0,0);
  else if (b < 8576)  build_one(PF1 ,2,32,(b- 7552 )*256+tid, enc_W2,enc_b2,0,0);
  else if (b < 9600)  build_one(PF2 ,2,32,(b- 8576 )*256+tid, dec_W1,dec_b1,0,0);
  else if (b < 10624) build_one(PF3 ,2,32,(b- 9600 )*256+tid, dec_W2,dec_b2,0,0);
  else if (b < 10656) build_one(ZFR ,3, 1,(b-10624 )*256+tid, zm_W,zm_b,zs_W,zs_b);
  else if (b < 10848) build_one(HFR ,4, 6,(b-10656 )*256+tid, xm_W,xm_b,xs_W,xs_b);
  else if (b == 10848){
    if (tid < 20){
      int l = tid;
      float w0 = flow_w[l*3+0], w1 = flow_w[l*3+1], w2 = flow_w[l*3+2];
      float u0 = flow_u[l*3+0], u1 = flow_u[l*3+1], u2 = flow_u[l*3+2];
      float wu = w0*u0 + w1*u1 + w2*u2;
      float m  = -1.f + fast_softplus(wu);
      float ww = w0*w0 + w1*w1 + w2*w2 + 1e-7f;
      float sc = (m - wu) / ww;
      float uh0 = u0 + sc*w0, uh1 = u1 + sc*w1, uh2 = u2 + sc*w2;
      float uw  = uh0*w0 + uh1*w1 + uh2*w2;
      FPP[l*8+0]=w0; FPP[l*8+1]=w1; FPP[l*8+2]=w2; FPP[l*8+3]=flow_b[l];
      FPP[l*8+4]=uh0; FPP[l*8+5]=uh1; FPP[l*8+6]=uh2; FPP[l*8+7]=uw;
    }
  } else {
    for (int i = tid; i < 8192; i += 256) CNT[i] = 0;   // enc+dec counter arrays
  }
}

// ---------------------------------------------------------------------------
// Encoder input-gates precompute: gi[51200][1536] = x[51200][38] @ Wih^T + bih
// ---------------------------------------------------------------------------
__global__ __launch_bounds__(512, 2) void gi_enc_kernel(
    const float* __restrict__ x, const u16* __restrict__ frag2,
    const float* __restrict__ bih, u16* __restrict__ gi)
{
  const int tid = threadIdx.x, lane = tid & 63, v = tid >> 6;
  const int q = lane >> 4, c = lane & 15;
  const size_t rowbase = (size_t)blockIdx.x * 32;
  u16 a[2][2][8];
  #pragma unroll
  for (int tile = 0; tile < 2; ++tile){
    const float* xr = x + (rowbase + tile*16 + c) * 38;
    #pragma unroll
    for (int j = 0; j < 8; ++j){
      int k0 = q*8 + j;
      a[tile][0][j] = f2bf(xr[k0]);
      int k1 = 32 + q*8 + j;
      a[tile][1][j] = (k1 < 38) ? f2bf(xr[k1]) : (u16)0;
    }
  }
  f32x4 acc[2][12];
  #pragma unroll
  for (int tile = 0; tile < 2; ++tile)
    #pragma unroll
    for (int i = 0; i < 12; ++i) acc[tile][i] = zero4();
  #pragma unroll
  for (int i = 0; i < 12; ++i){
    const int nt = v*12 + i;
    bf16x8 b0 = __builtin_bit_cast(bf16x8,
        *(const u16x8*)(frag2 + (((size_t)0*96 + nt)*64 + lane)*8));
    bf16x8 b1 = __builtin_bit_cast(bf16x8,
        *(const u16x8*)(frag2 + (((size_t)1*96 + nt)*64 + lane)*8));
    #pragma unroll
    for (int tile = 0; tile < 2; ++tile){
      bf16x8 a0 = __builtin_bit_cast(bf16x8, *(const u16x8*)a[tile][0]);
      bf16x8 a1 = __builtin_bit_cast(bf16x8, *(const u16x8*)a[tile][1]);
      acc[tile][i] = MFMA16x16(a0, b0, acc[tile][i]);
      acc[tile][i] = MFMA16x16(a1, b1, acc[tile][i]);
    }
  }
  #pragma unroll
  for (int i = 0; i < 12; ++i){
    const int nt = v*12 + i;
    const int ncol = nt*16 + c;
    const int g = ncol >> 9, jin = ncol & 511;
    const float bias = (jin < 500) ? bih[g*500 + jin] : 0.f;
    #pragma unroll
    for (int tile = 0; tile < 2; ++tile)
      #pragma unroll
      for (int r = 0; r < 4; ++r){
        size_t row = rowbase + tile*16 + q*4 + r;
        gi[row*1536 + ncol] = f2bf(acc[tile][i][r] + bias);
      }
  }
}

// ---------------------------------------------------------------------------
// GRU v7: R3's proven counter sync + LDS-staged h exchange.
// Change vs gru6: the h-tile (16 KB) is loaded from IF ONCE per block
// (each of the 8 waves loads a distinct 2 KB slice, sc1) into a padded LDS
// tile (row stride 260 u32 -> A-frag ds_read_b128 is conflict-floor), then
// all waves read fragments from LDS. Cuts IF read traffic 4x (64->16 KB
// per block per step) and the post-barrier IF burst that was queueing on
// the critical path. Poll loop spin without s_sleep.
// Grid 256 = 32 batch-groups x 8 col-slices; 8 waves = 4 nt x 2 K-halves.
// LDS 83840 B forces 1 block/CU.
// ---------------------------------------------------------------------------
__global__ __launch_bounds__(512, 2) void gru7_kernel(
    const u16* __restrict__ frag, const u16* __restrict__ gix,
    const u64* __restrict__ zsrc, const float* __restrict__ Wih3,
    const float* __restrict__ bih3,
    u32* __restrict__ hbufbase, u16* __restrict__ hout, u32* __restrict__ cntbase)
{
  __shared__ u32 hstage[16 * 260];          // padded h tile (16640 B)
  __shared__ f32x4 red[4200];               // 67200 B; total 83840 -> 1 block/CU
  const int tid  = threadIdx.x, lane = tid & 63;
  const int wv   = tid >> 6, igrp = wv & 3, half = wv >> 2;
  const int q    = lane >> 4, c = lane & 15;
  const int gid  = blockIdx.x & 31, s = blockIdx.x >> 5;
  const int b0   = gid * 16;
  const int col  = (s*4 + igrp)*16 + c;
  u32* cnt = cntbase + gid * 128;           // 512 B stride
  u32* hb  = hbufbase + (size_t)gid * 8192; // 2 bufs x 16x256 u32

  // --- weights into VGPRs (held for all steps) ---
  u16x8 wf[3][8];
  #pragma unroll
  for (int kk = 0; kk < 8; ++kk){
    const int ks = half*8 + kk;
    #pragma unroll
    for (int g = 0; g < 3; ++g){
      const int nt = g*32 + s*4 + igrp;
      wf[g][kk] = *(const u16x8*)(frag + (((size_t)ks*96 + nt)*64 + lane)*8);
    }
  }
  // --- decoder-mode per-lane gi weights (z is rank 3) ---
  float wz[3][3] = {{0,0,0},{0,0,0},{0,0,0}}, wb[3] = {0,0,0};
  if (!gix && col < 500){
    #pragma unroll
    for (int g = 0; g < 3; ++g){
      #pragma unroll
      for (int k = 0; k < 3; ++k) wz[g][k] = Wih3[(g*500 + col)*3 + k];
      wb[g] = bih3[g*500 + col];
    }
  }

  // --- staging geometry: wave wv owns u32 lin = wv*512 + lane*8 .. +7 ---
  const int lin  = wv*512 + lane*8;
  const int srow = lin >> 8, scol = lin & 255;
  u32* sdst = hstage + srow*260 + scol;

  float hold[4] = {0.f, 0.f, 0.f, 0.f};
  u16 giv[3][4];
  u64 zv[4];
  if (half == 0){
    // h0 = 0 (+ col511 = 1.0), packed u32 pairs via IF (sc1)
    u32 me = (col == 511) ? 0x3F80u : 0u;
    u32 pr = __shfl_xor(me, 1, 64);
    if (!(c & 1)){
      u32 val = me | (pr << 16);
      #pragma unroll
      for (int r = 0; r < 4; ++r)
        __hip_atomic_store(hb + (q*4+r)*256 + (col>>1), val,
                           __ATOMIC_RELAXED, __HIP_MEMORY_SCOPE_AGENT);
    }
    // prefetch inputs for t=0
    if (gix){
      #pragma unroll
      for (int g = 0; g < 3; ++g)
        #pragma unroll
        for (int r = 0; r < 4; ++r)
          giv[g][r] = __builtin_nontemporal_load(
              gix + ((size_t)(b0 + q*4 + r)*100 + 0)*1536 + g*512 + col);
    } else {
      #pragma unroll
      for (int r = 0; r < 4; ++r)
        zv[r] = zsrc[(size_t)(b0 + q*4 + r)*100 + 0];
    }
  }
  __syncthreads();                          // drains vmcnt(0): h0 stores acked at IF
  if (tid == 0)
    __hip_atomic_fetch_add(cnt, 1u, __ATOMIC_RELAXED, __HIP_MEMORY_SCOPE_AGENT);

  #pragma unroll 1
  for (int t = 0; t < 100; ++t){
    if (tid == 0){
      const u32 target = 8u*(u32)(t+1);
      long guard = 0;
      while (__hip_atomic_load(cnt, __ATOMIC_RELAXED, __HIP_MEMORY_SCOPE_AGENT) < target){
        if (++guard > (1L<<27)) break;      // hang-breaker
      }
    }
    __syncthreads();                        // B1: h_t visible at IF

    // --- stage: 8 waves x 2 KB distinct slices, IF -> regs -> padded LDS ---
    {
      const u64* src = (const u64*)(hb + (t & 1)*4096 + lin);
      u64 s0 = __hip_atomic_load(src,     __ATOMIC_RELAXED, __HIP_MEMORY_SCOPE_AGENT);
      u64 s1 = __hip_atomic_load(src + 1, __ATOMIC_RELAXED, __HIP_MEMORY_SCOPE_AGENT);
      u64 s2 = __hip_atomic_load(src + 2, __ATOMIC_RELAXED, __HIP_MEMORY_SCOPE_AGENT);
      u64 s3 = __hip_atomic_load(src + 3, __ATOMIC_RELAXED, __HIP_MEMORY_SCOPE_AGENT);
      u32x4 w0, w1;
      w0[0] = (u32)s0; w0[1] = (u32)(s0 >> 32); w0[2] = (u32)s1; w0[3] = (u32)(s1 >> 32);
      w1[0] = (u32)s2; w1[1] = (u32)(s2 >> 32); w1[2] = (u32)s3; w1[3] = (u32)(s3 >> 32);
      *(u32x4*)(sdst)     = w0;
      *(u32x4*)(sdst + 4) = w1;
    }
    __syncthreads();                        // B2: staging complete

    f32x4 acc0 = zero4(), acc1 = zero4(), acc2 = zero4();
    #pragma unroll
    for (int kk = 0; kk < 8; ++kk){
      const int ks = half*8 + kk;
      bf16x8 af = *(const bf16x8*)&hstage[c*260 + ks*16 + q*4];
      acc0 = MFMA16x16(af, __builtin_bit_cast(bf16x8, wf[0][kk]), acc0);
      acc1 = MFMA16x16(af, __builtin_bit_cast(bf16x8, wf[1][kk]), acc1);
      acc2 = MFMA16x16(af, __builtin_bit_cast(bf16x8, wf[2][kk]), acc2);
    }
    if (half == 1){
      red[(igrp*3 + 0)*64 + lane] = acc0;
      red[(igrp*3 + 1)*64 + lane] = acc1;
      red[(igrp*3 + 2)*64 + lane] = acc2;
    }
    __syncthreads();                        // B3: partials in LDS
    u16 hvv[4];
    u32*       nxt   = hb + ((t+1) & 1)*4096;
    if (half == 0){
      const f32x4 p0 = red[(igrp*3+0)*64 + lane];
      const f32x4 p1 = red[(igrp*3+1)*64 + lane];
      const f32x4 p2 = red[(igrp*3+2)*64 + lane];
      #pragma unroll
      for (int r = 0; r < 4; ++r){
        float gr, gz, gn;
        if (gix){
          gr = bf2f(giv[0][r]); gz = bf2f(giv[1][r]); gn = bf2f(giv[2][r]);
        } else {
          float z0 = bf2f((u16)(zv[r]));
          float z1 = bf2f((u16)(zv[r] >> 16));
          float z2 = bf2f((u16)(zv[r] >> 32));
          gr = z0*wz[0][0] + z1*wz[0][1] + z2*wz[0][2] + wb[0];
          gz = z0*wz[1][0] + z1*wz[1][1] + z2*wz[1][2] + wb[1];
          gn = z0*wz[2][0] + z1*wz[2][1] + z2*wz[2][2] + wb[2];
        }
        float ar = acc0[r] + p0[r] + gr;
        float az = acc1[r] + p1[r] + gz;
        float an = acc2[r] + p2[r];
        float rr = fast_sigmoid(ar);
        float zz = fast_sigmoid(az);
        float nn = fast_tanh(gn + rr*an);
        float h  = (1.f - zz)*nn + zz*hold[r];
        hold[r] = h;
        u16 hv16 = (col < 500) ? f2bf(h) : ((col == 511) ? (u16)0x3F80 : (u16)0);
        hvv[r] = hv16;
        u32 me = hv16;
        u32 pr = __shfl_xor(me, 1, 64);
        if (!(c & 1))
          __hip_atomic_store(nxt + (q*4+r)*256 + (col>>1), me | (pr << 16),
                             __ATOMIC_RELAXED, __HIP_MEMORY_SCOPE_AGENT);
      }
    }
    __syncthreads();                        // B4: drains vmcnt -> stores at IF
    if (tid == 0)
      __hip_atomic_fetch_add(cnt, 1u, __ATOMIC_RELAXED, __HIP_MEMORY_SCOPE_AGENT);
    if (half == 0){
      #pragma unroll
      for (int r = 0; r < 4; ++r)
        __builtin_nontemporal_store(hvv[r],
            hout + ((size_t)(b0 + q*4 + r)*100 + t)*512 + col);
      if (t < 99){
        if (gix){
          #pragma unroll
          for (int g = 0; g < 3; ++g)
            #pragma unroll
            for (int r = 0; r < 4; ++r)
              giv[g][r] = __builtin_nontemporal_load(
                  gix + ((size_t)(b0 + q*4 + r)*100 + (t+1))*1536 + g*512 + col);
        } else {
          #pragma unroll
          for (int r = 0; r < 4; ++r)
            zv[r] = zsrc[(size_t)(b0 + q*4 + r)*100 + (t+1)];
        }
      }
    }
  }
}

// ---------------------------------------------------------------------------
// Fused post-net chain: P1 = lrelu(A@fA), P2 = lrelu(P1@fB), then
// mode 0: hm[51200][8] = P2 @ ZFR   mode 1: heads (mu, softplus std).
// ---------------------------------------------------------------------------
__global__ __launch_bounds__(512, 4) void post_chain(
    const u16* __restrict__ A, const u16* __restrict__ fA,
    const u16* __restrict__ fB, const u16* __restrict__ f3,
    float* __restrict__ o0, float* __restrict__ o1, int mode)
{
  __shared__ u16 AS[32768];                 // [rt4][ks16][qq4][m16][j8]
  const int tid = threadIdx.x, lane = tid & 63, w = tid >> 6;
  const int q = lane >> 4, c = lane & 15;
  const int rt = w & 3, nh = w >> 2;
  const size_t rowbase = (size_t)blockIdx.x * 64;

  // ---- stage 1 ----
  f32x4 acc[16];
  #pragma unroll
  for (int i = 0; i < 16; ++i) acc[i] = zero4();
  {
    const u16* Ar = A + (rowbase + rt*16 + c) * 512 + q * 8;
    #pragma unroll 1
    for (int ks = 0; ks < 16; ++ks){
      bf16x8 af = __builtin_bit_cast(bf16x8, *(const u16x8*)(Ar + ks * 32));
      #pragma unroll
      for (int i = 0; i < 16; ++i){
        const int nt = nh * 16 + i;
        bf16x8 bf = __builtin_bit_cast(bf16x8,
            *(const u16x8*)(fA + (((size_t)ks * 32 + nt) * 64 + lane) * 8));
        acc[i] = MFMA16x16(af, bf, acc[i]);
      }
    }
  }
  #pragma unroll
  for (int i = 0; i < 16; ++i){
    const int cl = (nh * 16 + i) * 16 + c;
    const int ks2 = cl >> 5, qq = (cl >> 3) & 3, j = cl & 7;
    #pragma unroll
    for (int r = 0; r < 4; ++r){
      const int m = q*4 + r;
      float v = acc[i][r];
      v = fmaxf(v, 0.1f * v);
      AS[(((rt*16 + ks2)*4 + qq)*16 + m)*8 + j] =
          (cl < 500) ? f2bf(v) : ((cl == 511) ? (u16)0x3F80 : (u16)0);
    }
  }
  __syncthreads();

  // ---- stage 2 ----
  #pragma unroll
  for (int i = 0; i < 16; ++i) acc[i] = zero4();
  #pragma unroll 1
  for (int ks = 0; ks < 16; ++ks){
    bf16x8 af = __builtin_bit_cast(bf16x8,
        *(const u16x8*)&AS[(((rt*16 + ks)*4 + q)*16 + c)*8]);
    #pragma unroll
    for (int i = 0; i < 16; ++i){
      const int nt = nh * 16 + i;
      bf16x8 bf = __builtin_bit_cast(bf16x8,
          *(const u16x8*)(fB + (((size_t)ks * 32 + nt) * 64 + lane) * 8));
      acc[i] = MFMA16x16(af, bf, acc[i]);
    }
  }
  __syncthreads();
  #pragma unroll
  for (int i = 0; i < 16; ++i){
    const int cl = (nh * 16 + i) * 16 + c;
    const int ks2 = cl >> 5, qq = (cl >> 3) & 3, j = cl & 7;
    #pragma unroll
    for (int r = 0; r < 4; ++r){
      const int m = q*4 + r;
      float v = acc[i][r];
      v = fmaxf(v, 0.1f * v);
      AS[(((rt*16 + ks2)*4 + qq)*16 + m)*8 + j] =
          (cl < 500) ? f2bf(v) : ((cl == 511) ? (u16)0x3F80 : (u16)0);
    }
  }
  __syncthreads();

  // ---- stage 3 ----
  if (mode == 0){
    if (w < 4){
      const int rt3 = w;
      f32x4 a3 = zero4();
      #pragma unroll 1
      for (int ks = 0; ks < 16; ++ks){
        bf16x8 af = __builtin_bit_cast(bf16x8,
            *(const u16x8*)&AS[(((rt3*16 + ks)*4 + q)*16 + c)*8]);
        bf16x8 bf = __builtin_bit_cast(bf16x8,
            *(const u16x8*)(f3 + (((size_t)ks * 64) + lane) * 8));
        a3 = MFMA16x16(af, bf, a3);
      }
      if (c < 6){
        #pragma unroll
        for (int r = 0; r < 4; ++r)
          o0[(rowbase + rt3*16 + q*4 + r)*8 + c] = a3[r];
      }
    }
  } else {
    const int rt3 = w & 3, hh = w >> 2;
    f32x4 a3[3];
    #pragma unroll
    for (int ii = 0; ii < 3; ++ii) a3[ii] = zero4();
    #pragma unroll 1
    for (int ks = 0; ks < 16; ++ks){
      bf16x8 af = __builtin_bit_cast(bf16x8,
          *(const u16x8*)&AS[(((rt3*16 + ks)*4 + q)*16 + c)*8]);
      #pragma unroll
      for (int ii = 0; ii < 3; ++ii){
        const int nt = hh*3 + ii;
        bf16x8 bf = __builtin_bit_cast(bf16x8,
            *(const u16x8*)(f3 + (((size_t)ks * 6 + nt) * 64 + lane) * 8));
        a3[ii] = MFMA16x16(af, bf, a3[ii]);
      }
    }
    #pragma unroll
    for (int ii = 0; ii < 3; ++ii){
      const int cc = (hh*3 + ii)*16 + c;
      const int grp = cc / 48;
      const int cl = cc - grp * 48;
      if (cl < 38){
        #pragma unroll
        for (int r = 0; r < 4; ++r){
          const size_t row = rowbase + rt3*16 + q*4 + r;
          if (grp == 0) o0[row*38 + cl] = a3[ii][r];
          else          o1[row*38 + cl] = fast_softplus(a3[ii][r]) + 1e-4f;
        }
      }
    }
  }
}

// ---------------------------------------------------------------------------
// Sequential latent scan: only the 3x3 z-feedback part (h-part precomputed).
// ---------------------------------------------------------------------------
__global__ void scan_kernel(const float* __restrict__ hm, const float* __restrict__ eps,
                            const float* __restrict__ zmW, const float* __restrict__ zsW,
                            float* __restrict__ zgen, float* __restrict__ zmu,
                            float* __restrict__ zstd)
{
  int b = blockIdx.x * blockDim.x + threadIdx.x;
  if (b >= 512) return;
  float Wm[3][3], Ws[3][3];
  #pragma unroll
  for (int j = 0; j < 3; ++j)
    #pragma unroll
    for (int k = 0; k < 3; ++k){
      Wm[j][k] = zmW[j * 503 + 500 + k];
      Ws[j][k] = zsW[j * 503 + 500 + k];
    }
  float z0 = 0.f, z1 = 0.f, z2 = 0.f;
  for (int t = 0; t < 100; ++t){
    size_t row = (size_t)b * 100 + t;
    const float* h = hm + row * 8;
    const float* e = eps + row * 3;
    float zn[3];
    #pragma unroll
    for (int j = 0; j < 3; ++j){
      float m_ = h[j]     + Wm[j][0]*z0 + Wm[j][1]*z1 + Wm[j][2]*z2;
      float p_ = h[3 + j] + Ws[j][0]*z0 + Ws[j][1]*z1 + Ws[j][2]*z2;
      float s_ = fast_softplus(p_) + 1e-4f;
      float zv = m_ + s_ * e[j];
      zgen[row * 3 + j] = zv;
      zmu [row * 3 + j] = m_;
      zstd[row * 3 + j] = s_;
      zn[j] = zv;
    }
    z0 = zn[0]; z1 = zn[1]; z2 = zn[2];
  }
}

// ---------------------------------------------------------------------------
// Planar flow (parallel over 51200); also emits packed bf16 z for dec GRU.
// ---------------------------------------------------------------------------
__global__ void flow_kernel(const float* __restrict__ zgen, const float* __restrict__ fp,
                            float* __restrict__ zfin, float* __restrict__ ldj,
                            u16* __restrict__ zf16)
{
  int idx = blockIdx.x * blockDim.x + threadIdx.x;
  if (idx >= 51200) return;
  float z0 = zgen[idx*3+0], z1 = zgen[idx*3+1], z2 = zgen[idx*3+2];
  float ld = 0.f;
  #pragma unroll 1
  for (int l = 0; l < 20; ++l){
    const float* p = fp + l * 8;
    float lin = z0*p[0] + z1*p[1] + z2*p[2] + p[3];
    float tt = fast_tanh(lin);
    z0 += p[4]*tt; z1 += p[5]*tt; z2 += p[6]*tt;
    float det = 1.f + (1.f - tt*tt) * p[7];
    ld += __logf(fabsf(det) + 1e-7f);
  }
  zfin[idx*3+0] = z0; zfin[idx*3+1] = z1; zfin[idx*3+2] = z2;
  ldj[idx] = ld;
  u16x4 o; o[0] = f2bf(z0); o[1] = f2bf(z1); o[2] = f2bf(z2); o[3] = 0x3F80;
  *(u16x4*)(zf16 + (size_t)idx * 4) = o;
}

// ---------------------------------------------------------------------------
extern "C" void kernel_launch(void* const* d_in, const int* in_sizes, int n_in,
                              void* d_out, int out_size, void* d_ws, size_t ws_size,
                              hipStream_t stream)
{
  const float* x       = (const float*)d_in[0];
  const float* eps     = (const float*)d_in[1];
  const float* enc_Wih = (const float*)d_in[2];
  const float* enc_Whh = (const float*)d_in[3];
  const float* enc_bih = (const float*)d_in[4];
  const float* enc_bhh = (const float*)d_in[5];
  const float* enc_W1  = (const float*)d_in[6];
  const float* enc_b1  = (const float*)d_in[7];
  const float* enc_W2  = (const float*)d_in[8];
  const float* enc_b2  = (const float*)d_in[9];
  const float* zm_W    = (const float*)d_in[10];
  const float* zm_b    = (const float*)d_in[11];
  const float* zs_W    = (const float*)d_in[12];
  const float* zs_b    = (const float*)d_in[13];
  const float* flow_w  = (const float*)d_in[14];
  const float* flow_b  = (const float*)d_in[15];
  const float* flow_u  = (const float*)d_in[16];
  const float* dec_Wih = (const float*)d_in[17];
  const float* dec_Whh = (const float*)d_in[18];
  const float* dec_bih = (const float*)d_in[19];
  const float* dec_bhh = (const float*)d_in[20];
  const float* dec_W1  = (const float*)d_in[21];
  const float* dec_b1  = (const float*)d_in[22];
  const float* dec_W2  = (const float*)d_in[23];
  const float* dec_b2  = (const float*)d_in[24];
  const float* xm_W    = (const float*)d_in[25];
  const float* xm_b    = (const float*)d_in[26];
  const float* xs_W    = (const float*)d_in[27];
  const float* xs_b    = (const float*)d_in[28];
  (void)in_sizes; (void)n_in; (void)out_size; (void)ws_size;

  float* out    = (float*)d_out;
  float* r_mu   = out;                 // [512,100,38]
  float* r_std  = out + 1945600;       // [512,100,38]
  float* r_zgen = out + 3891200;       // [512,100,3]
  float* r_zfin = out + 4044800;       // [512,100,3]
  float* r_zmu  = out + 4198400;       // [512,100,3]
  float* r_zstd = out + 4352000;       // [512,100,3]
  float* r_ldj  = out + 4505600;       // [512,100,1]

  char* ws = (char*)d_ws;
  size_t off = 0;
  auto alloc = [&](size_t bytes)->char*{
    char* p = ws + off;
    off += (bytes + 255) & ~(size_t)255;
    return p;
  };
  u16* H1    = (u16*)alloc((size_t)51200*512*2);     // GRU hidden states
  u16* BIG   = (u16*)alloc((size_t)51200*1536*2);    // enc gi buffer
  u16* ENCF  = (u16*)alloc((size_t)16*96*512*2);
  u16* DECF  = (u16*)alloc((size_t)16*96*512*2);
  u16* EGIF  = (u16*)alloc((size_t)2*96*512*2);
  u16* PF0   = (u16*)alloc((size_t)16*32*512*2);
  u16* PF1   = (u16*)alloc((size_t)16*32*512*2);
  u16* PF2   = (u16*)alloc((size_t)16*32*512*2);
  u16* PF3   = (u16*)alloc((size_t)16*32*512*2);
  u16* ZFR   = (u16*)alloc((size_t)16*1*512*2);
  u16* HFR   = (u16*)alloc((size_t)16*6*512*2);
  float* FPP = (float*)alloc((size_t)20*8*4);
  float* HM  = (float*)alloc((size_t)51200*8*4);
  u16* ZF16  = (u16*)alloc((size_t)51200*4*2);
  u32* HBUF  = (u32*)alloc((size_t)32*2*16*512*2);   // h exchange (packed bf16 pairs)
  u32* CNT   = (u32*)alloc((size_t)2*32*128*4);      // 512 B/group counters, enc+dec

  build_all<<<10850,256,0,stream>>>(ENCF,DECF,EGIF,PF0,PF1,PF2,PF3,ZFR,HFR,FPP,CNT,
      enc_Whh,enc_bhh,enc_Wih,dec_Whh,dec_bhh,
      enc_W1,enc_b1,enc_W2,enc_b2,dec_W1,dec_b1,dec_W2,dec_b2,
      zm_W,zm_b,zs_W,zs_b,xm_W,xm_b,xs_W,xs_b,flow_w,flow_b,flow_u);

  // --- encoder ---
  gi_enc_kernel<<<1600,512,0,stream>>>(x, EGIF, enc_bih, BIG);
  gru7_kernel<<<256,512,0,stream>>>(ENCF, BIG, nullptr, nullptr, nullptr,
                                    HBUF, H1, CNT);
  post_chain<<<800,512,0,stream>>>(H1, PF0, PF1, ZFR, HM, nullptr, 0);

  // --- latent scan + planar flow ---
  scan_kernel<<<2,256,0,stream>>>(HM, eps, zm_W, zs_W, r_zgen, r_zmu, r_zstd);
  flow_kernel<<<200,256,0,stream>>>(r_zgen, FPP, r_zfin, r_ldj, ZF16);

  // --- decoder ---
  gru7_kernel<<<256,512,0,stream>>>(DECF, nullptr, (const u64*)ZF16,
                                    dec_Wih, dec_bih, HBUF, H1, CNT + 32*128);
  post_chain<<<800,512,0,stream>>>(H1, PF2, PF3, HFR, r_mu, r_std, 1);
}

// Round 9
// 1205.976 us; speedup vs baseline: 1.9076x; 1.0737x over previous
//
#include <hip/hip_runtime.h>

typedef unsigned short u16;
typedef unsigned int u32;
typedef unsigned long long u64;
typedef __bf16 bf16x8 __attribute__((ext_vector_type(8)));
typedef float f32x4 __attribute__((ext_vector_type(4)));
typedef u16 u16x8 __attribute__((ext_vector_type(8)));
typedef u16 u16x4 __attribute__((ext_vector_type(4)));
typedef u32 u32x4 __attribute__((ext_vector_type(4)));

#define MFMA16x16(a,b,c) __builtin_amdgcn_mfma_f32_16x16x32_bf16((a),(b),(c),0,0,0)

static __device__ __forceinline__ u16 f2bf(float f){
  u32 u = __builtin_bit_cast(u32, f);
  u += 0x7fffu + ((u >> 16) & 1u);
  return (u16)(u >> 16);
}
static __device__ __forceinline__ float bf2f(u16 h){
  u32 u = ((u32)h) << 16;
  return __builtin_bit_cast(float, u);
}
static __device__ __forceinline__ float fast_sigmoid(float x){
  return 1.f / (1.f + __expf(-x));
}
static __device__ __forceinline__ float fast_tanh(float x){
  float e = __expf(2.f * x);
  return 1.f - 2.f / (e + 1.f);
}
static __device__ __forceinline__ float fast_softplus(float x){
  return (x > 15.f) ? x : __logf(1.f + __expf(x));
}
static __device__ __forceinline__ f32x4 zero4(){
  f32x4 v; v[0]=0.f; v[1]=0.f; v[2]=0.f; v[3]=0.f; return v;
}

// ---------------------------------------------------------------------------
// Weight swizzle into MFMA B-fragment order:
// dst[ks][nt][lane][j] = W[k = ks*32 + (lane>>4)*8 + j][ncol = nt*16 + (lane&15)]
// modes: 0 GRU hidden  2 post(500x500+b)  3 zW  4 heads  5 enc Wih
// ---------------------------------------------------------------------------
static __device__ __forceinline__ void build_one(
    u16* __restrict__ dst, int mode, int NT, int idx,
    const float* __restrict__ W0, const float* __restrict__ b0,
    const float* __restrict__ W1, const float* __restrict__ b1)
{
  int j    = idx & 7;
  int lane = (idx >> 3) & 63;
  int ntks = idx >> 9;
  int nt   = ntks % NT;
  int ks   = ntks / NT;
  int k    = ks * 32 + ((lane >> 4) << 3) + j;
  int ncol = (nt << 4) + (lane & 15);
  float v = 0.f;
  if (mode == 0){                         // GRU hidden: rows 0..499 Whh^T, 511 bhh
    int g = ncol >> 9;
    int jin = ncol & 511;
    if (jin < 500){
      int row = g * 500 + jin;
      if (k < 500) v = W0[row * 500 + k];
      else if (k == 511) v = b0[row];
    }
  } else if (mode == 2){                  // post: W0 [500][500], bias row 511
    if (ncol < 500){
      if (k < 500) v = W0[ncol * 500 + k];
      else if (k == 511) v = b0[ncol];
    }
  } else if (mode == 3){                  // zW: cols 0..2 zm (W0 [3][503]), 3..5 zs
    int c = ncol;
    if (c < 3){
      if (k < 500) v = W0[c * 503 + k];
      else if (k == 511) v = b0[c];
    } else if (c < 6){
      int cc = c - 3;
      if (k < 500) v = W1[cc * 503 + k];
      else if (k == 511) v = b1[cc];
    }
  } else if (mode == 4){                  // heads: cols 0..47 xm (<38), 48..95 xs
    int grp = ncol / 48;
    int cc  = ncol - grp * 48;
    if (grp < 2 && cc < 38){
      const float* W  = grp ? W1 : W0;
      const float* bb = grp ? b1 : b0;
      if (k < 500) v = W[cc * 500 + k];
      else if (k == 511) v = bb[cc];
    }
  } else {                                // mode 5: enc Wih [1500][38]
    int g = ncol >> 9;
    int jin = ncol & 511;
    if (jin < 500 && k < 38) v = W0[(g * 500 + jin) * 38 + k];
  }
  dst[idx] = f2bf(v);
}

// One launch for all weight prep + flow params + counter zeroing.
__global__ void build_all(
    u16* ENCF, u16* DECF, u16* EGIF, u16* PF0, u16* PF1, u16* PF2, u16* PF3,
    u16* ZFR, u16* HFR, float* FPP, u32* CNT,
    const float* enc_Whh, const float* enc_bhh, const float* enc_Wih,
    const float* dec_Whh, const float* dec_bhh,
    const float* enc_W1, const float* enc_b1, const float* enc_W2, const float* enc_b2,
    const float* dec_W1, const float* dec_b1, const float* dec_W2, const float* dec_b2,
    const float* zm_W, const float* zm_b, const float* zs_W, const float* zs_b,
    const float* xm_W, const float* xm_b, const float* xs_W, const float* xs_b,
    const float* flow_w, const float* flow_b, const float* flow_u)
{
  const int b = blockIdx.x, tid = threadIdx.x;
  if      (b < 3072)  build_one(ENCF,0,96,(b       )*256+tid, enc_Whh,enc_bhh,0,0);
  else if (b < 6144)  build_one(DECF,0,96,(b- 3072 )*256+tid, dec_Whh,dec_bhh,0,0);
  else if (b < 6528)  build_one(EGIF,5,96,(b- 6144 )*256+tid, enc_Wih,0,0,0);
  else if (b < 7552)  build_one(PF0 ,2,32,(b- 6528 )*256+tid, enc_W1,enc_b1,0,0);
  else if (b < 8576)  build_one(PF1 ,2,32,(b- 7552 )*256+tid, enc_W2,enc_b2,0,0);
  else if (b < 9600)  build_one(PF2 ,2,32,(b- 8576 )*256+tid, dec_W1,dec_b1,0,0);
  else if (b < 10624) build_one(PF3 ,2,32,(b- 9600 )*256+tid, dec_W2,dec_b2,0,0);
  else if (b < 10656) build_one(ZFR ,3, 1,(b-10624 )*256+tid, zm_W,zm_b,zs_W,zs_b);
  else if (b < 10848) build_one(HFR ,4, 6,(b-10656 )*256+tid, xm_W,xm_b,xs_W,xs_b);
  else if (b == 10848){
    if (tid < 20){
      int l = tid;
      float w0 = flow_w[l*3+0], w1 = flow_w[l*3+1], w2 = flow_w[l*3+2];
      float u0 = flow_u[l*3+0], u1 = flow_u[l*3+1], u2 = flow_u[l*3+2];
      float wu = w0*u0 + w1*u1 + w2*u2;
      float m  = -1.f + fast_softplus(wu);
      float ww = w0*w0 + w1*w1 + w2*w2 + 1e-7f;
      float sc = (m - wu) / ww;
      float uh0 = u0 + sc*w0, uh1 = u1 + sc*w1, uh2 = u2 + sc*w2;
      float uw  = uh0*w0 + uh1*w1 + uh2*w2;
      FPP[l*8+0]=w0; FPP[l*8+1]=w1; FPP[l*8+2]=w2; FPP[l*8+3]=flow_b[l];
      FPP[l*8+4]=uh0; FPP[l*8+5]=uh1; FPP[l*8+6]=uh2; FPP[l*8+7]=uw;
    }
  } else {
    for (int i = tid; i < 8192; i += 256) CNT[i] = 0;   // enc+dec counter arrays
  }
}

// ---------------------------------------------------------------------------
// Encoder input-gates precompute: gi[51200][1536] = x[51200][38] @ Wih^T + bih
// ---------------------------------------------------------------------------
__global__ __launch_bounds__(512, 2) void gi_enc_kernel(
    const float* __restrict__ x, const u16* __restrict__ frag2,
    const float* __restrict__ bih, u16* __restrict__ gi)
{
  const int tid = threadIdx.x, lane = tid & 63, v = tid >> 6;
  const int q = lane >> 4, c = lane & 15;
  const size_t rowbase = (size_t)blockIdx.x * 32;
  u16 a[2][2][8];
  #pragma unroll
  for (int tile = 0; tile < 2; ++tile){
    const float* xr = x + (rowbase + tile*16 + c) * 38;
    #pragma unroll
    for (int j = 0; j < 8; ++j){
      int k0 = q*8 + j;
      a[tile][0][j] = f2bf(xr[k0]);
      int k1 = 32 + q*8 + j;
      a[tile][1][j] = (k1 < 38) ? f2bf(xr[k1]) : (u16)0;
    }
  }
  f32x4 acc[2][12];
  #pragma unroll
  for (int tile = 0; tile < 2; ++tile)
    #pragma unroll
    for (int i = 0; i < 12; ++i) acc[tile][i] = zero4();
  #pragma unroll
  for (int i = 0; i < 12; ++i){
    const int nt = v*12 + i;
    bf16x8 b0 = __builtin_bit_cast(bf16x8,
        *(const u16x8*)(frag2 + (((size_t)0*96 + nt)*64 + lane)*8));
    bf16x8 b1 = __builtin_bit_cast(bf16x8,
        *(const u16x8*)(frag2 + (((size_t)1*96 + nt)*64 + lane)*8));
    #pragma unroll
    for (int tile = 0; tile < 2; ++tile){
      bf16x8 a0 = __builtin_bit_cast(bf16x8, *(const u16x8*)a[tile][0]);
      bf16x8 a1 = __builtin_bit_cast(bf16x8, *(const u16x8*)a[tile][1]);
      acc[tile][i] = MFMA16x16(a0, b0, acc[tile][i]);
      acc[tile][i] = MFMA16x16(a1, b1, acc[tile][i]);
    }
  }
  #pragma unroll
  for (int i = 0; i < 12; ++i){
    const int nt = v*12 + i;
    const int ncol = nt*16 + c;
    const int g = ncol >> 9, jin = ncol & 511;
    const float bias = (jin < 500) ? bih[g*500 + jin] : 0.f;
    #pragma unroll
    for (int tile = 0; tile < 2; ++tile)
      #pragma unroll
      for (int r = 0; r < 4; ++r){
        size_t row = rowbase + tile*16 + q*4 + r;
        gi[row*1536 + ncol] = f2bf(acc[tile][i][r] + bias);
      }
  }
}

// ---------------------------------------------------------------------------
// GRU v8: full-K waves, no cross-wave reduction.
// Grid 256 = 32 groups x 8 blocks; block = 256 thr = 4 waves; wave owns
// nt = s*4 + wv (16 cols) and computes the FULL K=512 (48 MFMAs, weights
// 192 VGPRs; 1 wave/SIMD -> 512-VGPR budget). No red[] roundtrip, no idle
// half: all waves run the epilogue. Own h slice written straight to LDS
// (never re-read from IF); 7 remote 2 KB slices staged with 7 overlapped
// u64 loads/thread (1 RT). Counter sync = R3's proven scheme.
// Barriers/step: B1 detect-bcast, B2 stage done, B3 mfma reads done,
// B4 vmcnt drain (stores acked at IF) -> signal.
// hstage declared 20800 u32 (83.2 KB) -> 1 block/CU.
// ---------------------------------------------------------------------------
__global__ __launch_bounds__(256, 1) void gru8_kernel(
    const u16* __restrict__ frag, const u16* __restrict__ gix,
    const u64* __restrict__ zsrc, const float* __restrict__ Wih3,
    const float* __restrict__ bih3,
    u32* __restrict__ hbufbase, u16* __restrict__ hout, u32* __restrict__ cntbase)
{
  __shared__ u32 hstage[20800];             // rows 0..15, stride 260; tail = ballast
  const int tid  = threadIdx.x, lane = tid & 63;
  const int wv   = tid >> 6;                // 0..3
  const int q    = lane >> 4, c = lane & 15;
  const int gid  = blockIdx.x & 31, s = blockIdx.x >> 5;   // s = 0..7
  const int b0   = gid * 16;
  const int nt0  = s*4 + wv;                // 0..31
  const int col  = nt0*16 + c;
  u32* cnt = cntbase + gid * 128;           // 512 B stride
  u32* hb  = hbufbase + (size_t)gid * 8192; // 2 bufs x 16x256 u32

  // --- weights into VGPRs: 3 gates x 16 ks (held for all steps) ---
  u16x8 wf[3][16];
  #pragma unroll
  for (int ks = 0; ks < 16; ++ks)
    #pragma unroll
    for (int g = 0; g < 3; ++g)
      wf[g][ks] = *(const u16x8*)(frag + (((size_t)ks*96 + g*32 + nt0)*64 + lane)*8);

  // --- decoder-mode per-lane gi weights (z is rank 3) ---
  float wz[3][3] = {{0,0,0},{0,0,0},{0,0,0}}, wb[3] = {0,0,0};
  if (!gix && col < 500){
    #pragma unroll
    for (int g = 0; g < 3; ++g){
      #pragma unroll
      for (int k = 0; k < 3; ++k) wz[g][k] = Wih3[(g*500 + col)*3 + k];
      wb[g] = bih3[g*500 + col];
    }
  }

  // --- staging geometry: thread stages 1 u64 per remote slice ---
  const int srow = tid >> 4;                // 0..15
  const int spos = (tid & 15) * 2;          // u32 offset within 32-u32 slice row

  float hold[4] = {0.f, 0.f, 0.f, 0.f};
  u16 giv[3][4];
  u64 zv[4];
  {
    // h0 = 0 (+ col511 = 1.0): own LDS copy + IF copy for remote blocks
    u32 me = (col == 511) ? 0x3F80u : 0u;
    u32 pr = __shfl_xor(me, 1, 64);
    if (!(c & 1)){
      u32 val = me | (pr << 16);
      #pragma unroll
      for (int r = 0; r < 4; ++r){
        hstage[(q*4+r)*260 + (col>>1)] = val;
        __hip_atomic_store(hb + (q*4+r)*256 + (col>>1), val,
                           __ATOMIC_RELAXED, __HIP_MEMORY_SCOPE_AGENT);
      }
    }
    // prefetch inputs for t=0
    if (gix){
      #pragma unroll
      for (int g = 0; g < 3; ++g)
        #pragma unroll
        for (int r = 0; r < 4; ++r)
          giv[g][r] = __builtin_nontemporal_load(
              gix + ((size_t)(b0 + q*4 + r)*100 + 0)*1536 + g*512 + col);
    } else {
      #pragma unroll
      for (int r = 0; r < 4; ++r)
        zv[r] = zsrc[(size_t)(b0 + q*4 + r)*100 + 0];
    }
  }
  __syncthreads();                          // drains vmcnt(0): h0 stores acked at IF
  if (tid == 0)
    __hip_atomic_fetch_add(cnt, 1u, __ATOMIC_RELAXED, __HIP_MEMORY_SCOPE_AGENT);

  #pragma unroll 1
  for (int t = 0; t < 100; ++t){
    if (tid == 0){
      const u32 target = 8u*(u32)(t+1);
      int guard = 0;
      while (__hip_atomic_load(cnt, __ATOMIC_RELAXED, __HIP_MEMORY_SCOPE_AGENT) < target){
        if (++guard > (1<<24)) break;       // hang-breaker
      }
    }
    __syncthreads();                        // B1: h_t visible at IF

    // --- stage 7 remote slices (overlapped u64 loads -> 1 RT) ---
    {
      const u64* src = (const u64*)(hb + (t & 1)*4096);
      u64 sv[7];
      #pragma unroll
      for (int r = 0; r < 7; ++r){
        const int rs = (s + 1 + r) & 7;
        sv[r] = __hip_atomic_load(src + srow*128 + rs*16 + (tid & 15),
                                  __ATOMIC_RELAXED, __HIP_MEMORY_SCOPE_AGENT);
      }
      #pragma unroll
      for (int r = 0; r < 7; ++r){
        const int rs = (s + 1 + r) & 7;
        *(u64*)&hstage[srow*260 + rs*32 + spos] = sv[r];
      }
    }
    __syncthreads();                        // B2: full h_t tile in LDS

    f32x4 acc0 = zero4(), acc1 = zero4(), acc2 = zero4();
    #pragma unroll
    for (int ks = 0; ks < 16; ++ks){
      bf16x8 af = *(const bf16x8*)&hstage[c*260 + ks*16 + q*4];
      acc0 = MFMA16x16(af, __builtin_bit_cast(bf16x8, wf[0][ks]), acc0);
      acc1 = MFMA16x16(af, __builtin_bit_cast(bf16x8, wf[1][ks]), acc1);
      acc2 = MFMA16x16(af, __builtin_bit_cast(bf16x8, wf[2][ks]), acc2);
    }
    __syncthreads();                        // B3: all mfma LDS reads done

    u16 hvv[4];
    u32* nxt = hb + ((t+1) & 1)*4096;
    {
      #pragma unroll
      for (int r = 0; r < 4; ++r){
        float gr, gz, gn;
        if (gix){
          gr = bf2f(giv[0][r]); gz = bf2f(giv[1][r]); gn = bf2f(giv[2][r]);
        } else {
          float z0 = bf2f((u16)(zv[r]));
          float z1 = bf2f((u16)(zv[r] >> 16));
          float z2 = bf2f((u16)(zv[r] >> 32));
          gr = z0*wz[0][0] + z1*wz[0][1] + z2*wz[0][2] + wb[0];
          gz = z0*wz[1][0] + z1*wz[1][1] + z2*wz[1][2] + wb[1];
          gn = z0*wz[2][0] + z1*wz[2][1] + z2*wz[2][2] + wb[2];
        }
        float ar = acc0[r] + gr;
        float az = acc1[r] + gz;
        float an = acc2[r];
        float rr = fast_sigmoid(ar);
        float zz = fast_sigmoid(az);
        float nn = fast_tanh(gn + rr*an);
        float h  = (1.f - zz)*nn + zz*hold[r];
        hold[r] = h;
        u16 hv16 = (col < 500) ? f2bf(h) : ((col == 511) ? (u16)0x3F80 : (u16)0);
        hvv[r] = hv16;
        u32 me = hv16;
        u32 pr = __shfl_xor(me, 1, 64);
        if (!(c & 1)){
          u32 val = me | (pr << 16);
          hstage[(q*4+r)*260 + (col>>1)] = val;     // own slice -> LDS for t+1
          __hip_atomic_store(nxt + (q*4+r)*256 + (col>>1), val,
                             __ATOMIC_RELAXED, __HIP_MEMORY_SCOPE_AGENT);
        }
      }
    }
    __syncthreads();                        // B4: drains vmcnt -> stores at IF
    if (tid == 0)
      __hip_atomic_fetch_add(cnt, 1u, __ATOMIC_RELAXED, __HIP_MEMORY_SCOPE_AGENT);
    // off-critical-path: hout + next-input prefetch
    #pragma unroll
    for (int r = 0; r < 4; ++r)
      __builtin_nontemporal_store(hvv[r],
          hout + ((size_t)(b0 + q*4 + r)*100 + t)*512 + col);
    if (t < 99){
      if (gix){
        #pragma unroll
        for (int g = 0; g < 3; ++g)
          #pragma unroll
          for (int r = 0; r < 4; ++r)
            giv[g][r] = __builtin_nontemporal_load(
                gix + ((size_t)(b0 + q*4 + r)*100 + (t+1))*1536 + g*512 + col);
      } else {
        #pragma unroll
        for (int r = 0; r < 4; ++r)
          zv[r] = zsrc[(size_t)(b0 + q*4 + r)*100 + (t+1)];
      }
    }
  }
}

// ---------------------------------------------------------------------------
// Fused post-net chain: P1 = lrelu(A@fA), P2 = lrelu(P1@fB), then
// mode 0: hm[51200][8] = P2 @ ZFR   mode 1: heads (mu, softplus std).
// ---------------------------------------------------------------------------
__global__ __launch_bounds__(512, 4) void post_chain(
    const u16* __restrict__ A, const u16* __restrict__ fA,
    const u16* __restrict__ fB, const u16* __restrict__ f3,
    float* __restrict__ o0, float* __restrict__ o1, int mode)
{
  __shared__ u16 AS[32768];                 // [rt4][ks16][qq4][m16][j8]
  const int tid = threadIdx.x, lane = tid & 63, w = tid >> 6;
  const int q = lane >> 4, c = lane & 15;
  const int rt = w & 3, nh = w >> 2;
  const size_t rowbase = (size_t)blockIdx.x * 64;

  // ---- stage 1 ----
  f32x4 acc[16];
  #pragma unroll
  for (int i = 0; i < 16; ++i) acc[i] = zero4();
  {
    const u16* Ar = A + (rowbase + rt*16 + c) * 512 + q * 8;
    #pragma unroll 1
    for (int ks = 0; ks < 16; ++ks){
      bf16x8 af = __builtin_bit_cast(bf16x8, *(const u16x8*)(Ar + ks * 32));
      #pragma unroll
      for (int i = 0; i < 16; ++i){
        const int nt = nh * 16 + i;
        bf16x8 bf = __builtin_bit_cast(bf16x8,
            *(const u16x8*)(fA + (((size_t)ks * 32 + nt) * 64 + lane) * 8));
        acc[i] = MFMA16x16(af, bf, acc[i]);
      }
    }
  }
  #pragma unroll
  for (int i = 0; i < 16; ++i){
    const int cl = (nh * 16 + i) * 16 + c;
    const int ks2 = cl >> 5, qq = (cl >> 3) & 3, j = cl & 7;
    #pragma unroll
    for (int r = 0; r < 4; ++r){
      const int m = q*4 + r;
      float v = acc[i][r];
      v = fmaxf(v, 0.1f * v);
      AS[(((rt*16 + ks2)*4 + qq)*16 + m)*8 + j] =
          (cl < 500) ? f2bf(v) : ((cl == 511) ? (u16)0x3F80 : (u16)0);
    }
  }
  __syncthreads();

  // ---- stage 2 ----
  #pragma unroll
  for (int i = 0; i < 16; ++i) acc[i] = zero4();
  #pragma unroll 1
  for (int ks = 0; ks < 16; ++ks){
    bf16x8 af = __builtin_bit_cast(bf16x8,
        *(const u16x8*)&AS[(((rt*16 + ks)*4 + q)*16 + c)*8]);
    #pragma unroll
    for (int i = 0; i < 16; ++i){
      const int nt = nh * 16 + i;
      bf16x8 bf = __builtin_bit_cast(bf16x8,
          *(const u16x8*)(fB + (((size_t)ks * 32 + nt) * 64 + lane) * 8));
      acc[i] = MFMA16x16(af, bf, acc[i]);
    }
  }
  __syncthreads();
  #pragma unroll
  for (int i = 0; i < 16; ++i){
    const int cl = (nh * 16 + i) * 16 + c;
    const int ks2 = cl >> 5, qq = (cl >> 3) & 3, j = cl & 7;
    #pragma unroll
    for (int r = 0; r < 4; ++r){
      const int m = q*4 + r;
      float v = acc[i][r];
      v = fmaxf(v, 0.1f * v);
      AS[(((rt*16 + ks2)*4 + qq)*16 + m)*8 + j] =
          (cl < 500) ? f2bf(v) : ((cl == 511) ? (u16)0x3F80 : (u16)0);
    }
  }
  __syncthreads();

  // ---- stage 3 ----
  if (mode == 0){
    if (w < 4){
      const int rt3 = w;
      f32x4 a3 = zero4();
      #pragma unroll 1
      for (int ks = 0; ks < 16; ++ks){
        bf16x8 af = __builtin_bit_cast(bf16x8,
            *(const u16x8*)&AS[(((rt3*16 + ks)*4 + q)*16 + c)*8]);
        bf16x8 bf = __builtin_bit_cast(bf16x8,
            *(const u16x8*)(f3 + (((size_t)ks * 64) + lane) * 8));
        a3 = MFMA16x16(af, bf, a3);
      }
      if (c < 6){
        #pragma unroll
        for (int r = 0; r < 4; ++r)
          o0[(rowbase + rt3*16 + q*4 + r)*8 + c] = a3[r];
      }
    }
  } else {
    const int rt3 = w & 3, hh = w >> 2;
    f32x4 a3[3];
    #pragma unroll
    for (int ii = 0; ii < 3; ++ii) a3[ii] = zero4();
    #pragma unroll 1
    for (int ks = 0; ks < 16; ++ks){
      bf16x8 af = __builtin_bit_cast(bf16x8,
          *(const u16x8*)&AS[(((rt3*16 + ks)*4 + q)*16 + c)*8]);
      #pragma unroll
      for (int ii = 0; ii < 3; ++ii){
        const int nt = hh*3 + ii;
        bf16x8 bf = __builtin_bit_cast(bf16x8,
            *(const u16x8*)(f3 + (((size_t)ks * 6 + nt) * 64 + lane) * 8));
        a3[ii] = MFMA16x16(af, bf, a3[ii]);
      }
    }
    #pragma unroll
    for (int ii = 0; ii < 3; ++ii){
      const int cc = (hh*3 + ii)*16 + c;
      const int grp = cc / 48;
      const int cl = cc - grp * 48;
      if (cl < 38){
        #pragma unroll
        for (int r = 0; r < 4; ++r){
          const size_t row = rowbase + rt3*16 + q*4 + r;
          if (grp == 0) o0[row*38 + cl] = a3[ii][r];
          else          o1[row*38 + cl] = fast_softplus(a3[ii][r]) + 1e-4f;
        }
      }
    }
  }
}

// ---------------------------------------------------------------------------
// Sequential latent scan: only the 3x3 z-feedback part (h-part precomputed).
// ---------------------------------------------------------------------------
__global__ void scan_kernel(const float* __restrict__ hm, const float* __restrict__ eps,
                            const float* __restrict__ zmW, const float* __restrict__ zsW,
                            float* __restrict__ zgen, float* __restrict__ zmu,
                            float* __restrict__ zstd)
{
  int b = blockIdx.x * blockDim.x + threadIdx.x;
  if (b >= 512) return;
  float Wm[3][3], Ws[3][3];
  #pragma unroll
  for (int j = 0; j < 3; ++j)
    #pragma unroll
    for (int k = 0; k < 3; ++k){
      Wm[j][k] = zmW[j * 503 + 500 + k];
      Ws[j][k] = zsW[j * 503 + 500 + k];
    }
  float z0 = 0.f, z1 = 0.f, z2 = 0.f;
  for (int t = 0; t < 100; ++t){
    size_t row = (size_t)b * 100 + t;
    const float* h = hm + row * 8;
    const float* e = eps + row * 3;
    float zn[3];
    #pragma unroll
    for (int j = 0; j < 3; ++j){
      float m_ = h[j]     + Wm[j][0]*z0 + Wm[j][1]*z1 + Wm[j][2]*z2;
      float p_ = h[3 + j] + Ws[j][0]*z0 + Ws[j][1]*z1 + Ws[j][2]*z2;
      float s_ = fast_softplus(p_) + 1e-4f;
      float zv = m_ + s_ * e[j];
      zgen[row * 3 + j] = zv;
      zmu [row * 3 + j] = m_;
      zstd[row * 3 + j] = s_;
      zn[j] = zv;
    }
    z0 = zn[0]; z1 = zn[1]; z2 = zn[2];
  }
}

// ---------------------------------------------------------------------------
// Planar flow (parallel over 51200); also emits packed bf16 z for dec GRU.
// ---------------------------------------------------------------------------
__global__ void flow_kernel(const float* __restrict__ zgen, const float* __restrict__ fp,
                            float* __restrict__ zfin, float* __restrict__ ldj,
                            u16* __restrict__ zf16)
{
  int idx = blockIdx.x * blockDim.x + threadIdx.x;
  if (idx >= 51200) return;
  float z0 = zgen[idx*3+0], z1 = zgen[idx*3+1], z2 = zgen[idx*3+2];
  float ld = 0.f;
  #pragma unroll 1
  for (int l = 0; l < 20; ++l){
    const float* p = fp + l * 8;
    float lin = z0*p[0] + z1*p[1] + z2*p[2] + p[3];
    float tt = fast_tanh(lin);
    z0 += p[4]*tt; z1 += p[5]*tt; z2 += p[6]*tt;
    float det = 1.f + (1.f - tt*tt) * p[7];
    ld += __logf(fabsf(det) + 1e-7f);
  }
  zfin[idx*3+0] = z0; zfin[idx*3+1] = z1; zfin[idx*3+2] = z2;
  ldj[idx] = ld;
  u16x4 o; o[0] = f2bf(z0); o[1] = f2bf(z1); o[2] = f2bf(z2); o[3] = 0x3F80;
  *(u16x4*)(zf16 + (size_t)idx * 4) = o;
}

// ---------------------------------------------------------------------------
extern "C" void kernel_launch(void* const* d_in, const int* in_sizes, int n_in,
                              void* d_out, int out_size, void* d_ws, size_t ws_size,
                              hipStream_t stream)
{
  const float* x       = (const float*)d_in[0];
  const float* eps     = (const float*)d_in[1];
  const float* enc_Wih = (const float*)d_in[2];
  const float* enc_Whh = (const float*)d_in[3];
  const float* enc_bih = (const float*)d_in[4];
  const float* enc_bhh = (const float*)d_in[5];
  const float* enc_W1  = (const float*)d_in[6];
  const float* enc_b1  = (const float*)d_in[7];
  const float* enc_W2  = (const float*)d_in[8];
  const float* enc_b2  = (const float*)d_in[9];
  const float* zm_W    = (const float*)d_in[10];
  const float* zm_b    = (const float*)d_in[11];
  const float* zs_W    = (const float*)d_in[12];
  const float* zs_b    = (const float*)d_in[13];
  const float* flow_w  = (const float*)d_in[14];
  const float* flow_b  = (const float*)d_in[15];
  const float* flow_u  = (const float*)d_in[16];
  const float* dec_Wih = (const float*)d_in[17];
  const float* dec_Whh = (const float*)d_in[18];
  const float* dec_bih = (const float*)d_in[19];
  const float* dec_bhh = (const float*)d_in[20];
  const float* dec_W1  = (const float*)d_in[21];
  const float* dec_b1  = (const float*)d_in[22];
  const float* dec_W2  = (const float*)d_in[23];
  const float* dec_b2  = (const float*)d_in[24];
  const float* xm_W    = (const float*)d_in[25];
  const float* xm_b    = (const float*)d_in[26];
  const float* xs_W    = (const float*)d_in[27];
  const float* xs_b    = (const float*)d_in[28];
  (void)in_sizes; (void)n_in; (void)out_size; (void)ws_size;

  float* out    = (float*)d_out;
  float* r_mu   = out;                 // [512,100,38]
  float* r_std  = out + 1945600;       // [512,100,38]
  float* r_zgen = out + 3891200;       // [512,100,3]
  float* r_zfin = out + 4044800;       // [512,100,3]
  float* r_zmu  = out + 4198400;       // [512,100,3]
  float* r_zstd = out + 4352000;       // [512,100,3]
  float* r_ldj  = out + 4505600;       // [512,100,1]

  char* ws = (char*)d_ws;
  size_t off = 0;
  auto alloc = [&](size_t bytes)->char*{
    char* p = ws + off;
    off += (bytes + 255) & ~(size_t)255;
    return p;
  };
  u16* H1    = (u16*)alloc((size_t)51200*512*2);     // GRU hidden states
  u16* BIG   = (u16*)alloc((size_t)51200*1536*2);    // enc gi buffer
  u16* ENCF  = (u16*)alloc((size_t)16*96*512*2);
  u16* DECF  = (u16*)alloc((size_t)16*96*512*2);
  u16* EGIF  = (u16*)alloc((size_t)2*96*512*2);
  u16* PF0   = (u16*)alloc((size_t)16*32*512*2);
  u16* PF1   = (u16*)alloc((size_t)16*32*512*2);
  u16* PF2   = (u16*)alloc((size_t)16*32*512*2);
  u16* PF3   = (u16*)alloc((size_t)16*32*512*2);
  u16* ZFR   = (u16*)alloc((size_t)16*1*512*2);
  u16* HFR   = (u16*)alloc((size_t)16*6*512*2);
  float* FPP = (float*)alloc((size_t)20*8*4);
  float* HM  = (float*)alloc((size_t)51200*8*4);
  u16* ZF16  = (u16*)alloc((size_t)51200*4*2);
  u32* HBUF  = (u32*)alloc((size_t)32*2*16*512*2);   // h exchange (packed bf16 pairs)
  u32* CNT   = (u32*)alloc((size_t)2*32*128*4);      // 512 B/group counters, enc+dec

  build_all<<<10850,256,0,stream>>>(ENCF,DECF,EGIF,PF0,PF1,PF2,PF3,ZFR,HFR,FPP,CNT,
      enc_Whh,enc_bhh,enc_Wih,dec_Whh,dec_bhh,
      enc_W1,enc_b1,enc_W2,enc_b2,dec_W1,dec_b1,dec_W2,dec_b2,
      zm_W,zm_b,zs_W,zs_b,xm_W,xm_b,xs_W,xs_b,flow_w,flow_b,flow_u);

  // --- encoder ---
  gi_enc_kernel<<<1600,512,0,stream>>>(x, EGIF, enc_bih, BIG);
  gru8_kernel<<<256,256,0,stream>>>(ENCF, BIG, nullptr, nullptr, nullptr,
                                    HBUF, H1, CNT);
  post_chain<<<800,512,0,stream>>>(H1, PF0, PF1, ZFR, HM, nullptr, 0);

  // --- latent scan + planar flow ---
  scan_kernel<<<2,256,0,stream>>>(HM, eps, zm_W, zs_W, r_zgen, r_zmu, r_zstd);
  flow_kernel<<<200,256,0,stream>>>(r_zgen, FPP, r_zfin, r_ldj, ZF16);

  // --- decoder ---
  gru8_kernel<<<256,256,0,stream>>>(DECF, nullptr, (const u64*)ZF16,
                                    dec_Wih, dec_bih, HBUF, H1, CNT + 32*128);
  post_chain<<<800,512,0,stream>>>(H1, PF2, PF3, HFR, r_mu, r_std, 1);
}